// Round 7
// baseline (626.621 us; speedup 1.0000x reference)
//
#include <hip/hip_runtime.h>
#include <math.h>

#define L 4096
#define CDIM 256
#define DIN 512
#define DSTATE 16
#define DTR 16
#define BATCH 4

typedef unsigned short ushort_t;
using f32x4  = __attribute__((ext_vector_type(4))) float;
using bf16x8 = __attribute__((ext_vector_type(8))) __bf16;

__device__ __forceinline__ float silu_f(float x) { return x / (1.f + __expf(-x)); }
__device__ __forceinline__ float softplus_fast(float x) {
    return (x > 20.f) ? x : __logf(1.f + __expf(x));
}
// fp32 -> (hi, lo) bf16 truncation split: x ~= hi + lo, resid ~2^-17|x|
__device__ __forceinline__ void split1(float x, ushort_t &h, ushort_t &l) {
    unsigned hb = __float_as_uint(x) & 0xffff0000u;
    h = (ushort_t)(hb >> 16);
    float r = x - __uint_as_float(hb);
    l = (ushort_t)(__float_as_uint(r) >> 16);
}

enum { EPI_PLANES = 0, EPI_SPLITUZ = 1, EPI_D34 = 2, EPI_F32 = 3 };

// ---------------- split-bf16 MFMA GEMM, pre-split operand planes ----------------
// Out[b,m,n] = sum_k A[b,m,k] * Wt[n,k] via ah*bh + ah*bl + al*bh.
// A planes: [b][M][K] bf16(hi/lo) row-major. B planes: [N][K].
// Block tile M=128, N=64, K-step 32. k-loop has NO conversion math: uint4 loads only.
#define LDK 40
template<int EPI>
__global__ __launch_bounds__(256)
void mfma_gemm(const ushort_t* __restrict__ Ah_g, const ushort_t* __restrict__ Al_g,
               const ushort_t* __restrict__ Bh_g, const ushort_t* __restrict__ Bl_g,
               const float* __restrict__ bias,
               float* __restrict__ O0, float* __restrict__ O1, float* __restrict__ O2,
               ushort_t* __restrict__ Oh, ushort_t* __restrict__ Ol,
               int M, int N, int K, long strideAb, int nBlk)
{
    __shared__ __align__(16) ushort_t Ah[128][LDK], Al[128][LDK];
    __shared__ __align__(16) ushort_t Bh[64][LDK],  Bl[64][LDK];
    const int mBlk = M / 128;
    // XCD-sticky swizzle: n-blocks of one (b,m) A-tile share bid%8 -> same XCD L2
    const int bid = blockIdx.x;
    const int r = bid & 7, q = bid >> 3;
    const int ni = q % nBlk;
    const int mg = (q / nBlk) * 8 + r;
    const int b = mg / mBlk, m_idx = mg - b * mBlk;
    const int n0 = ni * 64, m0 = m_idx * 128;
    const int tid  = threadIdx.x;
    const int lane = tid & 63;
    const int w    = tid >> 6;
    const int lrow = lane & 15;
    const int loct = lane >> 4;

    f32x4 acc[2][4];
    #pragma unroll
    for (int i = 0; i < 2; ++i)
        #pragma unroll
        for (int j = 0; j < 4; ++j)
            acc[i][j] = (f32x4){0.f, 0.f, 0.f, 0.f};

    const int sOct = tid & 3, sRow = tid >> 2;   // A rows sRow,sRow+64; B row sRow
    uint4 pa[2][2], pb[2];

    auto loadTile = [&](int kk) {
        const long aoff = (long)b * strideAb + kk + sOct * 8;
        pa[0][0] = *(const uint4*)(Ah_g + aoff + (long)(m0 + sRow) * K);
        pa[0][1] = *(const uint4*)(Ah_g + aoff + (long)(m0 + sRow + 64) * K);
        pa[1][0] = *(const uint4*)(Al_g + aoff + (long)(m0 + sRow) * K);
        pa[1][1] = *(const uint4*)(Al_g + aoff + (long)(m0 + sRow + 64) * K);
        const int ng = n0 + sRow;
        if (EPI == EPI_D34 && ng >= N) {
            pb[0] = make_uint4(0, 0, 0, 0);
            pb[1] = make_uint4(0, 0, 0, 0);
        } else {
            pb[0] = *(const uint4*)(Bh_g + (long)ng * K + kk + sOct * 8);
            pb[1] = *(const uint4*)(Bl_g + (long)ng * K + kk + sOct * 8);
        }
    };
    auto storeTile = [&]() {
        *(uint4*)&Ah[sRow][sOct * 8]      = pa[0][0];
        *(uint4*)&Ah[sRow + 64][sOct * 8] = pa[0][1];
        *(uint4*)&Al[sRow][sOct * 8]      = pa[1][0];
        *(uint4*)&Al[sRow + 64][sOct * 8] = pa[1][1];
        *(uint4*)&Bh[sRow][sOct * 8]      = pb[0];
        *(uint4*)&Bl[sRow][sOct * 8]      = pb[1];
    };

    loadTile(0);
    for (int kk = 0; kk < K; kk += 32) {
        storeTile();
        __syncthreads();
        if (kk + 32 < K) loadTile(kk + 32);     // in flight during MFMA
        bf16x8 ah[2], al2[2], bh[4], bl2[4];
        #pragma unroll
        for (int mt = 0; mt < 2; ++mt) {
            ah[mt]  = *(const bf16x8*)&Ah[w*32 + mt*16 + lrow][loct*8];
            al2[mt] = *(const bf16x8*)&Al[w*32 + mt*16 + lrow][loct*8];
        }
        #pragma unroll
        for (int nt = 0; nt < 4; ++nt) {
            bh[nt]  = *(const bf16x8*)&Bh[nt*16 + lrow][loct*8];
            bl2[nt] = *(const bf16x8*)&Bl[nt*16 + lrow][loct*8];
        }
        #pragma unroll
        for (int mt = 0; mt < 2; ++mt)
            #pragma unroll
            for (int nt = 0; nt < 4; ++nt) {
                acc[mt][nt] = __builtin_amdgcn_mfma_f32_16x16x32_bf16(ah[mt],  bh[nt],  acc[mt][nt], 0, 0, 0);
                acc[mt][nt] = __builtin_amdgcn_mfma_f32_16x16x32_bf16(ah[mt],  bl2[nt], acc[mt][nt], 0, 0, 0);
                acc[mt][nt] = __builtin_amdgcn_mfma_f32_16x16x32_bf16(al2[mt], bh[nt],  acc[mt][nt], 0, 0, 0);
            }
        __syncthreads();
    }
    // ---- epilogue: C/D col=lane&15, row=(lane>>4)*4+reg ----
    #pragma unroll
    for (int mt = 0; mt < 2; ++mt) {
        #pragma unroll
        for (int r4 = 0; r4 < 4; ++r4) {
            int m = m0 + w * 32 + mt * 16 + loct * 4 + r4;
            long rowb = (long)b * M + m;
            #pragma unroll
            for (int nt = 0; nt < 4; ++nt) {
                int n = n0 + nt * 16 + lrow;
                float v = acc[mt][nt][r4];
                if (EPI == EPI_PLANES) {
                    v += bias[n];
                    split1(v, Oh[rowb * N + n], Ol[rowb * N + n]);
                } else if (EPI == EPI_SPLITUZ) {
                    if (n < DIN) O0[rowb * DIN + n] = v;
                    else         O1[rowb * DIN + (n - DIN)] = v;
                } else if (EPI == EPI_D34) {
                    if (n < DIN)            O0[rowb * DIN + n] = softplus_fast(v + bias[n]);
                    else if (n < DIN + 16)  O1[rowb * 16 + (n - DIN)] = v;
                    else if (n < DIN + 32)  O2[rowb * 16 + (n - DIN - 16)] = v;
                } else {  // EPI_F32
                    O0[rowb * N + n] = v;
                }
            }
        }
    }
}

// ---------------- weight fp32 -> hi/lo plane convert ----------------
__global__ __launch_bounds__(256)
void convert_weight(const float* __restrict__ W, ushort_t* __restrict__ Wh,
                    ushort_t* __restrict__ Wl, int n)
{
    int i = blockIdx.x * 256 + threadIdx.x;
    if (i < n) split1(W[i], Wh[i], Wl[i]);
}

// ---------------- Wcomb[544][512]: rows<512 = Wdt@Wx[:16]; rows 512..543 = Wx[16:48] ----------------
__global__ __launch_bounds__(256)
void weff_kernel(const float* __restrict__ Wdt, const float* __restrict__ Wx,
                 ushort_t* __restrict__ Wch, ushort_t* __restrict__ Wcl)
{
    int idx = blockIdx.x * 256 + threadIdx.x;   // n*512 + k, n < 544
    int n = idx >> 9, k = idx & 511;
    float acc;
    if (n < DIN) {
        acc = 0.f;
        #pragma unroll
        for (int r = 0; r < DTR; ++r)
            acc += Wdt[n * DTR + r] * Wx[r * DIN + k];
    } else {
        acc = Wx[(DTR + (n - DIN)) * DIN + k];
    }
    split1(acc, Wch[idx], Wcl[idx]);
}

// ---------------- x_cat transpose (c-major -> l-major) + split convert ----------------
__global__ __launch_bounds__(256)
void xcat_kernel(const float* __restrict__ sp, const float* __restrict__ fq,
                 ushort_t* __restrict__ Xh, ushort_t* __restrict__ Xl)
{
    __shared__ float tile[32][33];
    const int b = blockIdx.z, c0 = blockIdx.y * 32, l0 = blockIdx.x * 32;
    const int t = threadIdx.x;
    const int tc = t >> 5, tl = t & 31;
    #pragma unroll
    for (int p = 0; p < 4; ++p) {
        int c = c0 + tc + p * 8;
        float v = (c < CDIM) ? sp[((long)b * CDIM + c) * L + l0 + tl]
                             : fq[((long)b * CDIM + (c - CDIM)) * L + l0 + tl];
        tile[tc + p * 8][tl] = v;
    }
    __syncthreads();
    #pragma unroll
    for (int p = 0; p < 4; ++p) {
        int ll = tc + p * 8, cc = tl;
        long o = ((long)b * L + l0 + ll) * (2 * CDIM) + c0 + cc;
        split1(tile[cc][ll], Xh[o], Xl[o]);
    }
}

// ---------------- depthwise causal conv (k=4) + silu, writes fp32 + planes ----------------
__global__ __launch_bounds__(256)
void conv_silu_kernel(const float* __restrict__ u_pre, const float* __restrict__ cw,
                      const float* __restrict__ cb, float* __restrict__ u,
                      ushort_t* __restrict__ uh, ushort_t* __restrict__ ul)
{
    long idx = (long)blockIdx.x * blockDim.x + threadIdx.x;
    int d = (int)(idx % DIN);
    long bl = idx / DIN;
    int l = (int)(bl % L);
    long brow = bl - l;
    float v = cb[d];
    #pragma unroll
    for (int j = 0; j < 4; ++j) {
        int li = l - 3 + j;
        if (li >= 0) v += u_pre[(brow + li) * DIN + d] * cw[d * 4 + j];
    }
    float s = silu_f(v);
    u[idx] = s;
    split1(s, uh[idx], ul[idx]);
}

// ---------------- chunked parallel selective scan, d-per-lane ----------------
#define NC 128
#define LC (L / NC)

__global__ __launch_bounds__(256)
void scan_phase1(const float* __restrict__ delta, const float* __restrict__ u,
                 const float* __restrict__ Bm, const float* __restrict__ A_log,
                 float* __restrict__ Asum, float* __restrict__ Xsum)
{
    __shared__ float sB[LC][DSTATE];
    const int gd = blockIdx.x & 1;
    const int c  = (blockIdx.x >> 1) & (NC - 1);
    const int b  = blockIdx.x >> 8;
    const int d  = gd * 256 + threadIdx.x;
    const int t0 = c * LC;
    float Arow[DSTATE];
    #pragma unroll
    for (int q = 0; q < 4; ++q) {
        float4 v = *(const float4*)&A_log[d * DSTATE + q * 4];
        Arow[q * 4 + 0] = -__expf(v.x);
        Arow[q * 4 + 1] = -__expf(v.y);
        Arow[q * 4 + 2] = -__expf(v.z);
        Arow[q * 4 + 3] = -__expf(v.w);
    }
    for (int i = threadIdx.x; i < LC * DSTATE; i += 256)
        sB[i >> 4][i & 15] = Bm[((long)b * L + t0 + (i >> 4)) * DSTATE + (i & 15)];
    __syncthreads();
    float P[DSTATE], X[DSTATE];
    #pragma unroll
    for (int s = 0; s < DSTATE; ++s) { P[s] = 1.f; X[s] = 0.f; }
    for (int t = 0; t < LC; ++t) {
        long gidx = ((long)b * L + t0 + t) * DIN + d;
        float dlt = delta[gidx];
        float du  = dlt * u[gidx];
        #pragma unroll
        for (int s = 0; s < DSTATE; ++s) {
            float a = __expf(dlt * Arow[s]);
            P[s] *= a;
            X[s] = a * X[s] + du * sB[t][s];
        }
    }
    long o = (((long)b * NC + c) * DIN + d) * DSTATE;
    #pragma unroll
    for (int q = 0; q < 4; ++q) {
        *(float4*)&Asum[o + q * 4] = make_float4(P[q*4], P[q*4+1], P[q*4+2], P[q*4+3]);
        *(float4*)&Xsum[o + q * 4] = make_float4(X[q*4], X[q*4+1], X[q*4+2], X[q*4+3]);
    }
}

__global__ __launch_bounds__(256)
void scan_phase2(const float* __restrict__ Asum, float* __restrict__ Xsum)
{
    int lane = blockIdx.x * 256 + threadIdx.x;
    int b = lane / (DIN * DSTATE);
    int rem = lane % (DIN * DSTATE);
    float h = 0.f;
    for (int c = 0; c < NC; ++c) {
        long idx = ((long)b * NC + c) * (DIN * DSTATE) + rem;
        float A = Asum[idx], X = Xsum[idx];
        Xsum[idx] = h;
        h = A * h + X;
    }
}

__global__ __launch_bounds__(256)
void scan_phase3(const float* __restrict__ delta, const float* __restrict__ u,
                 const float* __restrict__ Bm, const float* __restrict__ Cm,
                 const float* __restrict__ z, const float* __restrict__ A_log,
                 const float* __restrict__ Dp, const float* __restrict__ Hinit,
                 ushort_t* __restrict__ y2h, ushort_t* __restrict__ y2l)
{
    __shared__ float sB[LC][DSTATE], sC[LC][DSTATE];
    const int gd = blockIdx.x & 1;
    const int c  = (blockIdx.x >> 1) & (NC - 1);
    const int b  = blockIdx.x >> 8;
    const int d  = gd * 256 + threadIdx.x;
    const int t0 = c * LC;
    float Arow[DSTATE];
    #pragma unroll
    for (int q = 0; q < 4; ++q) {
        float4 v = *(const float4*)&A_log[d * DSTATE + q * 4];
        Arow[q * 4 + 0] = -__expf(v.x);
        Arow[q * 4 + 1] = -__expf(v.y);
        Arow[q * 4 + 2] = -__expf(v.z);
        Arow[q * 4 + 3] = -__expf(v.w);
    }
    for (int i = threadIdx.x; i < LC * DSTATE; i += 256) {
        long gidx = ((long)b * L + t0 + (i >> 4)) * DSTATE + (i & 15);
        sB[i >> 4][i & 15] = Bm[gidx];
        sC[i >> 4][i & 15] = Cm[gidx];
    }
    float h[DSTATE];
    {
        long o = (((long)b * NC + c) * DIN + d) * DSTATE;
        #pragma unroll
        for (int q = 0; q < 4; ++q) {
            float4 v = *(const float4*)&Hinit[o + q * 4];
            h[q * 4 + 0] = v.x; h[q * 4 + 1] = v.y;
            h[q * 4 + 2] = v.z; h[q * 4 + 3] = v.w;
        }
    }
    const float Dval = Dp[d];
    __syncthreads();
    for (int t = 0; t < LC; ++t) {
        long gidx = ((long)b * L + t0 + t) * DIN + d;
        float dlt = delta[gidx];
        float uu  = u[gidx];
        float zz  = z[gidx];
        float du  = dlt * uu;
        float y = 0.f;
        #pragma unroll
        for (int s = 0; s < DSTATE; ++s) {
            float a = __expf(dlt * Arow[s]);
            h[s] = h[s] * a + du * sB[t][s];
            y += h[s] * sC[t][s];
        }
        float val = (y + uu * Dval) * silu_f(zz);
        split1(val, y2h[gidx], y2l[gidx]);
    }
}

// ---------------- LayerNorm over C + transpose to (B,C,L) ----------------
__global__ __launch_bounds__(256)
void ln_kernel(const float* __restrict__ X, const float* __restrict__ gamma,
               const float* __restrict__ beta, float* __restrict__ out)
{
    __shared__ float tile[32][257];
    __shared__ float sMu[32], sRs[32];
    const int l0 = blockIdx.x * 32;
    const int b  = blockIdx.y;
    const int tid = threadIdx.x;
    for (int i = tid; i < 32 * 256; i += 256) {
        int l = i >> 8, c = i & 255;
        tile[l][c] = X[((long)b * L + l0 + l) * CDIM + c];
    }
    __syncthreads();
    {
        int l = tid >> 3, sub = tid & 7;
        float s1 = 0.f, s2 = 0.f;
        for (int c = sub * 32; c < sub * 32 + 32; ++c) {
            float v = tile[l][c];
            s1 += v; s2 += v * v;
        }
        s1 += __shfl_xor(s1, 1); s2 += __shfl_xor(s2, 1);
        s1 += __shfl_xor(s1, 2); s2 += __shfl_xor(s2, 2);
        s1 += __shfl_xor(s1, 4); s2 += __shfl_xor(s2, 4);
        if (sub == 0) {
            float mu = s1 * (1.f / 256.f);
            float var = s2 * (1.f / 256.f) - mu * mu;
            sMu[l] = mu;
            sRs[l] = rsqrtf(var + 1e-5f);
        }
    }
    __syncthreads();
    for (int i = tid; i < 32 * 256; i += 256) {
        int ll = i & 31, c = i >> 5;
        float v = (tile[ll][c] - sMu[ll]) * sRs[ll] * gamma[c] + beta[c];
        out[((long)b * CDIM + c) * L + l0 + ll] = v;
    }
}

extern "C" void kernel_launch(void* const* d_in, const int* in_sizes, int n_in,
                              void* d_out, int out_size, void* d_ws, size_t ws_size,
                              hipStream_t stream)
{
    const float* sp   = (const float*)d_in[0];
    const float* fq   = (const float*)d_in[1];
    const float* Wp   = (const float*)d_in[2];
    const float* bp   = (const float*)d_in[3];
    const float* Win  = (const float*)d_in[4];
    const float* cw   = (const float*)d_in[5];
    const float* cb   = (const float*)d_in[6];
    const float* Wx   = (const float*)d_in[7];
    const float* Wdt  = (const float*)d_in[8];
    const float* bdt  = (const float*)d_in[9];
    const float* Alog = (const float*)d_in[10];
    const float* Dp   = (const float*)d_in[11];
    const float* Wout = (const float*)d_in[12];
    const float* gam  = (const float*)d_in[13];
    const float* bet  = (const float*)d_in[14];
    float* out = (float*)d_out;
    float* ws  = (float*)d_ws;

    const size_t NLD = (size_t)BATCH * L * DIN;     // 8.39M
    const size_t NLC = (size_t)BATCH * L * CDIM;    // 4.19M

    size_t off = 0;
    float* bufA  = ws + off; off += NLD;            // xcat planes -> later y2 planes
    float* bufB  = ws + off; off += NLC;            // xproj planes -> later x_mixed fp32
    float* u_pre = ws + off; off += NLD;            // pre-conv u -> later delta
    float* zb    = ws + off; off += NLD;
    float* ub    = ws + off; off += NLD;            // u fp32
    float* bufC  = ws + off; off += NLD;            // u planes -> later Asum+Xsum
    float* wbuf  = ws + off; off += 262144 + 131072 + 131072 + 278528; // Win,Wp,Wout,Wcomb planes
    float* Bmb   = ws + off; off += (size_t)BATCH * L * DSTATE;
    float* Cmb   = ws + off; off += (size_t)BATCH * L * DSTATE;

    ushort_t* xch = (ushort_t*)bufA;           ushort_t* xcl = xch + NLD;       // [b][l][512]
    ushort_t* xph = (ushort_t*)bufB;           ushort_t* xpl = xph + NLC;       // [b][l][256]
    ushort_t* uh  = (ushort_t*)bufC;           ushort_t* ul  = uh + NLD;        // [b][l][512]
    ushort_t* y2h = (ushort_t*)bufA;           ushort_t* y2l = y2h + NLD;       // reuse bufA
    float* Asum = bufC;                        float* Xsum = bufC + NLD / 2;    // reuse bufC
    float* xmix = bufB;                                                          // reuse bufB

    ushort_t* winh = (ushort_t*)wbuf;          ushort_t* winl = winh + 262144;
    ushort_t* wph  = winl + 262144;            ushort_t* wpl  = wph + 131072;
    ushort_t* woh  = wpl + 131072;             ushort_t* wol  = woh + 131072;
    ushort_t* wch  = wol + 131072;             ushort_t* wcl  = wch + 278528;

    dim3 blk(256);
    convert_weight<<<dim3(512), blk, 0, stream>>>(Wp, wph, wpl, 131072);
    convert_weight<<<dim3(1024), blk, 0, stream>>>(Win, winh, winl, 262144);
    convert_weight<<<dim3(512), blk, 0, stream>>>(Wout, woh, wol, 131072);
    weff_kernel<<<dim3(1088), blk, 0, stream>>>(Wdt, Wx, wch, wcl);
    xcat_kernel<<<dim3(L / 32, 512 / 32, BATCH), blk, 0, stream>>>(sp, fq, xch, xcl);

    // GEMM1: x_proj(planes) = x_cat @ Wp^T + bp
    mfma_gemm<EPI_PLANES><<<dim3(BATCH * (L/128) * 4), blk, 0, stream>>>(
        xch, xcl, wph, wpl, bp, nullptr, nullptr, nullptr, xph, xpl,
        L, CDIM, 2 * CDIM, (long)L * 2 * CDIM, 4);
    // GEMM2: xz = x_proj @ Win^T -> u_pre / z (fp32)
    mfma_gemm<EPI_SPLITUZ><<<dim3(BATCH * (L/128) * 16), blk, 0, stream>>>(
        xph, xpl, winh, winl, nullptr, u_pre, zb, nullptr, nullptr, nullptr,
        L, 2 * DIN, CDIM, (long)L * CDIM, 16);
    conv_silu_kernel<<<dim3((int)(NLD / 256)), blk, 0, stream>>>(u_pre, cw, cb, ub, uh, ul);
    // GEMM3+4 fused: [delta | Bm | Cm] = u @ Wcomb^T (delta into u_pre)
    mfma_gemm<EPI_D34><<<dim3(BATCH * (L/128) * 9), blk, 0, stream>>>(
        uh, ul, wch, wcl, bdt, u_pre, Bmb, Cmb, nullptr, nullptr,
        L, DIN + 32, DIN, (long)L * DIN, 9);

    scan_phase1<<<dim3(BATCH * NC * 2), blk, 0, stream>>>(u_pre, ub, Bmb, Alog, Asum, Xsum);
    scan_phase2<<<dim3(BATCH * DIN * DSTATE / 256), blk, 0, stream>>>(Asum, Xsum);
    scan_phase3<<<dim3(BATCH * NC * 2), blk, 0, stream>>>(
        u_pre, ub, Bmb, Cmb, zb, Alog, Dp, Xsum, y2h, y2l);

    // GEMM5: x_mixed = y2 @ Wout^T (fp32 out)
    mfma_gemm<EPI_F32><<<dim3(BATCH * (L/128) * 4), blk, 0, stream>>>(
        y2h, y2l, woh, wol, nullptr, xmix, nullptr, nullptr, nullptr, nullptr,
        L, CDIM, DIN, (long)L * DIN, 4);
    ln_kernel<<<dim3(L / 32, BATCH), blk, 0, stream>>>(xmix, gam, bet, out);
}

// Round 8
// 428.693 us; speedup vs baseline: 1.4617x; 1.4617x over previous
//
#include <hip/hip_runtime.h>
#include <math.h>

#define L 4096
#define CDIM 256
#define DIN 512
#define DSTATE 16
#define DTR 16
#define BATCH 4

using f32x4  = __attribute__((ext_vector_type(4))) float;
using bf16x8 = __attribute__((ext_vector_type(8))) __bf16;

__device__ __forceinline__ float silu_f(float x) { return x / (1.f + __expf(-x)); }
__device__ __forceinline__ float softplus_fast(float x) {
    return (x > 20.f) ? x : __logf(1.f + __expf(x));
}
// split fp32 -> (hi, lo) bf16 pair packed into uints; x ~= hi + lo, resid ~2^-17|x|
__device__ __forceinline__ void split_pack2(float x0, float x1, unsigned &h, unsigned &l) {
    unsigned b0 = __float_as_uint(x0), b1 = __float_as_uint(x1);
    h = (b0 >> 16) | (b1 & 0xffff0000u);
    float l0 = x0 - __uint_as_float(b0 & 0xffff0000u);
    float l1 = x1 - __uint_as_float(b1 & 0xffff0000u);
    l = (__float_as_uint(l0) >> 16) | (__float_as_uint(l1) & 0xffff0000u);
}

enum { EPI_BIAS = 0, EPI_SPLITUZ = 1, EPI_D34 = 2 };

// ---------------- split-bf16 MFMA GEMM (R6 structure: in-loop split = latency sponge) ----
// Out[b,m,n] = sum_k A[b,m,k] * Wt[n,k] via ah*bh + ah*bl + al*bh
// Block tile M=128, N=NT*16 (NT=4 or 8), K-step 32. LDS rows [row][40] (pad).
#define LDK 40
template<int EPI, bool A_KMAJOR, int NT>
__global__ __launch_bounds__(256)
void mfma_gemm(const float* __restrict__ A0, const float* __restrict__ A1,
               const float* __restrict__ Wt, const float* __restrict__ bias,
               float* __restrict__ O0, float* __restrict__ O1, float* __restrict__ O2,
               int M, int N, int K, int kSplit, long strideAb, int nBlk)
{
    __shared__ __align__(16) unsigned short Ah[128][LDK], Al[128][LDK];
    __shared__ __align__(16) unsigned short Bh[NT * 16][LDK], Bl[NT * 16][LDK];
    const int mBlk = M / 128;
    // XCD-sticky swizzle: n-blocks of one (b,m) A-tile share bid%8 -> same XCD L2
    const int bid = blockIdx.x;
    const int r = bid & 7, q = bid >> 3;
    const int ni = q % nBlk;
    const int mg = (q / nBlk) * 8 + r;
    const int b = mg / mBlk, m_idx = mg - b * mBlk;
    const int n0 = ni * (NT * 16), m0 = m_idx * 128;
    const int tid  = threadIdx.x;
    const int lane = tid & 63;
    const int w    = tid >> 6;
    const int lrow = lane & 15;
    const int loct = lane >> 4;

    f32x4 acc[2][NT];
    #pragma unroll
    for (int i = 0; i < 2; ++i)
        #pragma unroll
        for (int j = 0; j < NT; ++j)
            acc[i][j] = (f32x4){0.f, 0.f, 0.f, 0.f};

    const int sOct = tid & 3, sRow = tid >> 2;    // staging: row + 8-wide k-oct
    float va[16];
    float vb[(NT / 4) * 8];

    auto loadA = [&](int kk) {
        if (A_KMAJOR) {
            int m = tid & 127, half = tid >> 7;
            #pragma unroll
            for (int j = 0; j < 16; ++j) {
                int kg = kk + half * 16 + j;
                const float* Ap; int kl;
                if (kg < kSplit) { Ap = A0; kl = kg; } else { Ap = A1; kl = kg - kSplit; }
                va[j] = Ap[(long)b * strideAb + (long)kl * M + m0 + m];
            }
        } else {
            #pragma unroll
            for (int p = 0; p < 2; ++p) {
                const float* g = A0 + (long)b * strideAb + (long)(m0 + sRow + p * 64) * K + kk + sOct * 8;
                float4 x0 = *(const float4*)g;
                float4 x1 = *(const float4*)(g + 4);
                va[p*8+0] = x0.x; va[p*8+1] = x0.y; va[p*8+2] = x0.z; va[p*8+3] = x0.w;
                va[p*8+4] = x1.x; va[p*8+5] = x1.y; va[p*8+6] = x1.z; va[p*8+7] = x1.w;
            }
        }
    };
    auto loadB = [&](int kk) {
        #pragma unroll
        for (int p = 0; p < NT / 4; ++p) {
            int ng = n0 + sRow + p * 64;
            float4 x0 = make_float4(0.f, 0.f, 0.f, 0.f), x1 = x0;
            if (!(EPI == EPI_D34 && ng >= N)) {
                const float* g = Wt + (long)ng * K + kk + sOct * 8;
                x0 = *(const float4*)g; x1 = *(const float4*)(g + 4);
            }
            vb[p*8+0] = x0.x; vb[p*8+1] = x0.y; vb[p*8+2] = x0.z; vb[p*8+3] = x0.w;
            vb[p*8+4] = x1.x; vb[p*8+5] = x1.y; vb[p*8+6] = x1.z; vb[p*8+7] = x1.w;
        }
    };
    auto storeAB = [&]() {
        if (A_KMAJOR) {
            int m = tid & 127, half = tid >> 7;
            #pragma unroll
            for (int o = 0; o < 2; ++o) {
                uint4 h, l;
                split_pack2(va[o*8+0], va[o*8+1], h.x, l.x);
                split_pack2(va[o*8+2], va[o*8+3], h.y, l.y);
                split_pack2(va[o*8+4], va[o*8+5], h.z, l.z);
                split_pack2(va[o*8+6], va[o*8+7], h.w, l.w);
                *(uint4*)&Ah[m][half*16 + o*8] = h;
                *(uint4*)&Al[m][half*16 + o*8] = l;
            }
        } else {
            #pragma unroll
            for (int p = 0; p < 2; ++p) {
                uint4 h, l;
                split_pack2(va[p*8+0], va[p*8+1], h.x, l.x);
                split_pack2(va[p*8+2], va[p*8+3], h.y, l.y);
                split_pack2(va[p*8+4], va[p*8+5], h.z, l.z);
                split_pack2(va[p*8+6], va[p*8+7], h.w, l.w);
                *(uint4*)&Ah[sRow + p*64][sOct*8] = h;
                *(uint4*)&Al[sRow + p*64][sOct*8] = l;
            }
        }
        #pragma unroll
        for (int p = 0; p < NT / 4; ++p) {
            uint4 h, l;
            split_pack2(vb[p*8+0], vb[p*8+1], h.x, l.x);
            split_pack2(vb[p*8+2], vb[p*8+3], h.y, l.y);
            split_pack2(vb[p*8+4], vb[p*8+5], h.z, l.z);
            split_pack2(vb[p*8+6], vb[p*8+7], h.w, l.w);
            *(uint4*)&Bh[sRow + p*64][sOct*8] = h;
            *(uint4*)&Bl[sRow + p*64][sOct*8] = l;
        }
    };

    loadA(0); loadB(0);
    for (int kk = 0; kk < K; kk += 32) {
        storeAB();
        __syncthreads();
        if (kk + 32 < K) { loadA(kk + 32); loadB(kk + 32); }   // in flight during MFMA
        bf16x8 ah[2], al2[2], bh[NT], bl2[NT];
        #pragma unroll
        for (int mt = 0; mt < 2; ++mt) {
            ah[mt]  = *(const bf16x8*)&Ah[w*32 + mt*16 + lrow][loct*8];
            al2[mt] = *(const bf16x8*)&Al[w*32 + mt*16 + lrow][loct*8];
        }
        #pragma unroll
        for (int nt = 0; nt < NT; ++nt) {
            bh[nt]  = *(const bf16x8*)&Bh[nt*16 + lrow][loct*8];
            bl2[nt] = *(const bf16x8*)&Bl[nt*16 + lrow][loct*8];
        }
        #pragma unroll
        for (int mt = 0; mt < 2; ++mt)
            #pragma unroll
            for (int nt = 0; nt < NT; ++nt) {
                acc[mt][nt] = __builtin_amdgcn_mfma_f32_16x16x32_bf16(ah[mt],  bh[nt],  acc[mt][nt], 0, 0, 0);
                acc[mt][nt] = __builtin_amdgcn_mfma_f32_16x16x32_bf16(ah[mt],  bl2[nt], acc[mt][nt], 0, 0, 0);
                acc[mt][nt] = __builtin_amdgcn_mfma_f32_16x16x32_bf16(al2[mt], bh[nt],  acc[mt][nt], 0, 0, 0);
            }
        __syncthreads();
    }
    // ---- epilogue: C/D col=lane&15, row=(lane>>4)*4+reg ----
    #pragma unroll
    for (int mt = 0; mt < 2; ++mt) {
        #pragma unroll
        for (int r4 = 0; r4 < 4; ++r4) {
            int m = m0 + w * 32 + mt * 16 + loct * 4 + r4;
            long rowb = (long)b * M + m;
            #pragma unroll
            for (int nt = 0; nt < NT; ++nt) {
                int n = n0 + nt * 16 + lrow;
                float v = acc[mt][nt][r4];
                if (EPI == EPI_BIAS) {
                    if (bias) v += bias[n];
                    O0[rowb * N + n] = v;
                } else if (EPI == EPI_SPLITUZ) {
                    v += bias[n];
                    if (n < DIN) O0[rowb * DIN + n] = v;
                    else         O1[rowb * DIN + (n - DIN)] = v;
                } else if (EPI == EPI_D34) {
                    if (n < DIN)            O0[rowb * DIN + n] = softplus_fast(v + bias[n]);
                    else if (n < DIN + 16)  O1[rowb * 16 + (n - DIN)] = v;
                    else if (n < DIN + 32)  O2[rowb * 16 + (n - DIN - 16)] = v;
                }
            }
        }
    }
}

// ---------------- W2[1024][512] = Win @ Wp ; beff[1024] = Win @ bp ----------------
__global__ __launch_bounds__(256)
void weff2_kernel(const float* __restrict__ Win, const float* __restrict__ Wp,
                  const float* __restrict__ bp, float* __restrict__ W2,
                  float* __restrict__ beff)
{
    __shared__ float sWin[4][256];
    __shared__ float sbp[256];
    const int j0 = blockIdx.x * 4;
    const int tid = threadIdx.x;
    for (int i = tid; i < 4 * 256; i += 256)
        sWin[i >> 8][i & 255] = Win[(j0 + (i >> 8)) * 256 + (i & 255)];
    sbp[tid] = bp[tid];
    __syncthreads();
    float acc[4][2] = {};
    for (int c = 0; c < 256; ++c) {
        float w0 = Wp[c * 512 + tid];
        float w1 = Wp[c * 512 + tid + 256];
        #pragma unroll
        for (int jj = 0; jj < 4; ++jj) {
            acc[jj][0] += sWin[jj][c] * w0;
            acc[jj][1] += sWin[jj][c] * w1;
        }
    }
    #pragma unroll
    for (int jj = 0; jj < 4; ++jj) {
        W2[(j0 + jj) * 512 + tid]       = acc[jj][0];
        W2[(j0 + jj) * 512 + tid + 256] = acc[jj][1];
    }
    if (tid < 4) {
        float s = 0.f;
        for (int c = 0; c < 256; ++c) s += sbp[c] * sWin[tid][c];
        beff[j0 + tid] = s;
    }
}

// ---------------- Wcomb[544][512]: rows<512 = Wdt@Wx[:16]; rows 512.. = Wx[16:48] ----------------
__global__ __launch_bounds__(256)
void wcomb_kernel(const float* __restrict__ Wdt, const float* __restrict__ Wx,
                  float* __restrict__ Wc)
{
    int idx = blockIdx.x * 256 + threadIdx.x;   // n*512 + k, n < 544
    int n = idx >> 9, k = idx & 511;
    float acc;
    if (n < DIN) {
        acc = 0.f;
        #pragma unroll
        for (int r = 0; r < DTR; ++r)
            acc += Wdt[n * DTR + r] * Wx[r * DIN + k];
    } else {
        acc = Wx[(DTR + (n - DIN)) * DIN + k];
    }
    Wc[idx] = acc;
}

// ---------------- depthwise causal conv (k=4) + silu ----------------
__global__ __launch_bounds__(256)
void conv_silu_kernel(const float* __restrict__ u_pre, const float* __restrict__ cw,
                      const float* __restrict__ cb, float* __restrict__ u)
{
    long idx = (long)blockIdx.x * blockDim.x + threadIdx.x;
    int d = (int)(idx % DIN);
    long bl = idx / DIN;
    int l = (int)(bl % L);
    long brow = bl - l;
    float v = cb[d];
    #pragma unroll
    for (int j = 0; j < 4; ++j) {
        int li = l - 3 + j;
        if (li >= 0) v += u_pre[(brow + li) * DIN + d] * cw[d * 4 + j];
    }
    u[idx] = silu_f(v);
}

// ---------------- chunked parallel selective scan, d-per-lane ----------------
#define NC 128
#define LC (L / NC)

__global__ __launch_bounds__(256)
void scan_phase1(const float* __restrict__ delta, const float* __restrict__ u,
                 const float* __restrict__ Bm, const float* __restrict__ A_log,
                 float* __restrict__ Asum, float* __restrict__ Xsum)
{
    __shared__ float sB[LC][DSTATE];
    const int gd = blockIdx.x & 1;
    const int c  = (blockIdx.x >> 1) & (NC - 1);
    const int b  = blockIdx.x >> 8;
    const int d  = gd * 256 + threadIdx.x;
    const int t0 = c * LC;
    float Arow[DSTATE];
    #pragma unroll
    for (int q = 0; q < 4; ++q) {
        float4 v = *(const float4*)&A_log[d * DSTATE + q * 4];
        Arow[q * 4 + 0] = -__expf(v.x);
        Arow[q * 4 + 1] = -__expf(v.y);
        Arow[q * 4 + 2] = -__expf(v.z);
        Arow[q * 4 + 3] = -__expf(v.w);
    }
    for (int i = threadIdx.x; i < LC * DSTATE; i += 256)
        sB[i >> 4][i & 15] = Bm[((long)b * L + t0 + (i >> 4)) * DSTATE + (i & 15)];
    __syncthreads();
    float P[DSTATE], X[DSTATE];
    #pragma unroll
    for (int s = 0; s < DSTATE; ++s) { P[s] = 1.f; X[s] = 0.f; }
    for (int t = 0; t < LC; ++t) {
        long gidx = ((long)b * L + t0 + t) * DIN + d;
        float dlt = delta[gidx];
        float du  = dlt * u[gidx];
        #pragma unroll
        for (int s = 0; s < DSTATE; ++s) {
            float a = __expf(dlt * Arow[s]);
            P[s] *= a;
            X[s] = a * X[s] + du * sB[t][s];
        }
    }
    long o = (((long)b * NC + c) * DIN + d) * DSTATE;
    #pragma unroll
    for (int q = 0; q < 4; ++q) {
        *(float4*)&Asum[o + q * 4] = make_float4(P[q*4], P[q*4+1], P[q*4+2], P[q*4+3]);
        *(float4*)&Xsum[o + q * 4] = make_float4(X[q*4], X[q*4+1], X[q*4+2], X[q*4+3]);
    }
}

__global__ __launch_bounds__(256)
void scan_phase2(const float* __restrict__ Asum, float* __restrict__ Xsum)
{
    int lane = blockIdx.x * 256 + threadIdx.x;
    int b = lane / (DIN * DSTATE);
    int rem = lane % (DIN * DSTATE);
    float h = 0.f;
    for (int c = 0; c < NC; ++c) {
        long idx = ((long)b * NC + c) * (DIN * DSTATE) + rem;
        float A = Asum[idx], X = Xsum[idx];
        Xsum[idx] = h;
        h = A * h + X;
    }
}

__global__ __launch_bounds__(256)
void scan_phase3(const float* __restrict__ delta, const float* __restrict__ u,
                 const float* __restrict__ Bm, const float* __restrict__ Cm,
                 const float* __restrict__ z, const float* __restrict__ A_log,
                 const float* __restrict__ Dp, const float* __restrict__ Hinit,
                 float* __restrict__ y2)
{
    __shared__ float sB[LC][DSTATE], sC[LC][DSTATE];
    const int gd = blockIdx.x & 1;
    const int c  = (blockIdx.x >> 1) & (NC - 1);
    const int b  = blockIdx.x >> 8;
    const int d  = gd * 256 + threadIdx.x;
    const int t0 = c * LC;
    float Arow[DSTATE];
    #pragma unroll
    for (int q = 0; q < 4; ++q) {
        float4 v = *(const float4*)&A_log[d * DSTATE + q * 4];
        Arow[q * 4 + 0] = -__expf(v.x);
        Arow[q * 4 + 1] = -__expf(v.y);
        Arow[q * 4 + 2] = -__expf(v.z);
        Arow[q * 4 + 3] = -__expf(v.w);
    }
    for (int i = threadIdx.x; i < LC * DSTATE; i += 256) {
        long gidx = ((long)b * L + t0 + (i >> 4)) * DSTATE + (i & 15);
        sB[i >> 4][i & 15] = Bm[gidx];
        sC[i >> 4][i & 15] = Cm[gidx];
    }
    float h[DSTATE];
    {
        long o = (((long)b * NC + c) * DIN + d) * DSTATE;
        #pragma unroll
        for (int q = 0; q < 4; ++q) {
            float4 v = *(const float4*)&Hinit[o + q * 4];
            h[q * 4 + 0] = v.x; h[q * 4 + 1] = v.y;
            h[q * 4 + 2] = v.z; h[q * 4 + 3] = v.w;
        }
    }
    const float Dval = Dp[d];
    __syncthreads();
    for (int t = 0; t < LC; ++t) {
        long gidx = ((long)b * L + t0 + t) * DIN + d;
        float dlt = delta[gidx];
        float uu  = u[gidx];
        float zz  = z[gidx];
        float du  = dlt * uu;
        float y = 0.f;
        #pragma unroll
        for (int s = 0; s < DSTATE; ++s) {
            float a = __expf(dlt * Arow[s]);
            h[s] = h[s] * a + du * sB[t][s];
            y += h[s] * sC[t][s];
        }
        y2[gidx] = (y + uu * Dval) * silu_f(zz);
    }
}

// ---------------- LayerNorm over C + transpose to (B,C,L) ----------------
__global__ __launch_bounds__(256)
void ln_kernel(const float* __restrict__ X, const float* __restrict__ gamma,
               const float* __restrict__ beta, float* __restrict__ out)
{
    __shared__ float tile[32][257];
    __shared__ float sMu[32], sRs[32];
    const int l0 = blockIdx.x * 32;
    const int b  = blockIdx.y;
    const int tid = threadIdx.x;
    for (int i = tid; i < 32 * 256; i += 256) {
        int l = i >> 8, c = i & 255;
        tile[l][c] = X[((long)b * L + l0 + l) * CDIM + c];
    }
    __syncthreads();
    {
        int l = tid >> 3, sub = tid & 7;
        float s1 = 0.f, s2 = 0.f;
        for (int c = sub * 32; c < sub * 32 + 32; ++c) {
            float v = tile[l][c];
            s1 += v; s2 += v * v;
        }
        s1 += __shfl_xor(s1, 1); s2 += __shfl_xor(s2, 1);
        s1 += __shfl_xor(s1, 2); s2 += __shfl_xor(s2, 2);
        s1 += __shfl_xor(s1, 4); s2 += __shfl_xor(s2, 4);
        if (sub == 0) {
            float mu = s1 * (1.f / 256.f);
            float var = s2 * (1.f / 256.f) - mu * mu;
            sMu[l] = mu;
            sRs[l] = rsqrtf(var + 1e-5f);
        }
    }
    __syncthreads();
    for (int i = tid; i < 32 * 256; i += 256) {
        int ll = i & 31, c = i >> 5;
        float v = (tile[ll][c] - sMu[ll]) * sRs[ll] * gamma[c] + beta[c];
        out[((long)b * CDIM + c) * L + l0 + ll] = v;
    }
}

extern "C" void kernel_launch(void* const* d_in, const int* in_sizes, int n_in,
                              void* d_out, int out_size, void* d_ws, size_t ws_size,
                              hipStream_t stream)
{
    const float* sp   = (const float*)d_in[0];
    const float* fq   = (const float*)d_in[1];
    const float* Wp   = (const float*)d_in[2];
    const float* bp   = (const float*)d_in[3];
    const float* Win  = (const float*)d_in[4];
    const float* cw   = (const float*)d_in[5];
    const float* cb   = (const float*)d_in[6];
    const float* Wx   = (const float*)d_in[7];
    const float* Wdt  = (const float*)d_in[8];
    const float* bdt  = (const float*)d_in[9];
    const float* Alog = (const float*)d_in[10];
    const float* Dp   = (const float*)d_in[11];
    const float* Wout = (const float*)d_in[12];
    const float* gam  = (const float*)d_in[13];
    const float* bet  = (const float*)d_in[14];
    float* out = (float*)d_out;
    float* ws  = (float*)d_ws;

    const size_t NLD = (size_t)BATCH * L * DIN;   // 8.39M
    const size_t NLC = (size_t)BATCH * L * CDIM;  // 4.19M

    size_t off = 0;
    float* u_pre = ws + off; off += NLD;          // pre-conv u -> later delta
    float* zb    = ws + off; off += NLD;
    float* ub    = ws + off; off += NLD;
    float* yb    = ws + off; off += NLD;
    float* xmix  = ws + off; off += NLC;
    float* w2    = ws + off; off += (size_t)1024 * 512;
    float* beff  = ws + off; off += 1024;
    float* wcomb = ws + off; off += (size_t)544 * 512;
    float* Bmb   = ws + off; off += (size_t)BATCH * L * DSTATE;
    float* Cmb   = ws + off; off += (size_t)BATCH * L * DSTATE;
    float* Asum  = ws + off; off += (size_t)BATCH * NC * DIN * DSTATE;
    float* Xsum  = ws + off; off += (size_t)BATCH * NC * DIN * DSTATE;

    dim3 blk(256);
    // fold GEMM1 into GEMM2: W2 = Win@Wp, beff = Win@bp; Wcomb = [Wdt@Wx[:16] | Wx[16:48]]
    weff2_kernel<<<dim3(256), blk, 0, stream>>>(Win, Wp, bp, w2, beff);
    wcomb_kernel<<<dim3(544 * 512 / 256), blk, 0, stream>>>(Wdt, Wx, wcomb);

    // merged GEMM: xz = x_cat @ W2^T + beff -> u_pre / zb  (A K-major from sp/fq, NT=8)
    mfma_gemm<EPI_SPLITUZ, true, 8><<<dim3(BATCH * (L/128) * 8), blk, 0, stream>>>(
        sp, fq, w2, beff, u_pre, zb, nullptr,
        L, 2 * DIN, 2 * CDIM, CDIM, (long)CDIM * L, 8);

    conv_silu_kernel<<<dim3((int)(NLD / 256)), blk, 0, stream>>>(u_pre, cw, cb, ub);

    // D34: [delta | Bm | Cm] = u @ Wcomb^T, softplus on delta (into u_pre)
    mfma_gemm<EPI_D34, false, 4><<<dim3(BATCH * (L/128) * 9), blk, 0, stream>>>(
        ub, nullptr, wcomb, bdt, u_pre, Bmb, Cmb,
        L, 544, DIN, 1 << 30, (long)L * DIN, 9);

    scan_phase1<<<dim3(BATCH * NC * 2), blk, 0, stream>>>(u_pre, ub, Bmb, Alog, Asum, Xsum);
    scan_phase2<<<dim3(BATCH * DIN * DSTATE / 256), blk, 0, stream>>>(Asum, Xsum);
    scan_phase3<<<dim3(BATCH * NC * 2), blk, 0, stream>>>(
        u_pre, ub, Bmb, Cmb, zb, Alog, Dp, Xsum, yb);

    // GEMM5: x_mixed = y2 @ Wout^T
    mfma_gemm<EPI_BIAS, false, 4><<<dim3(BATCH * (L/128) * 4), blk, 0, stream>>>(
        yb, nullptr, Wout, nullptr, xmix, nullptr, nullptr,
        L, CDIM, DIN, 1 << 30, (long)L * DIN, 4);
    ln_kernel<<<dim3(L / 32, BATCH), blk, 0, stream>>>(xmix, gam, bet, out);
}

// Round 9
// 389.205 us; speedup vs baseline: 1.6100x; 1.1015x over previous
//
#include <hip/hip_runtime.h>
#include <math.h>

#define L 4096
#define CDIM 256
#define DIN 512
#define DSTATE 16
#define DTR 16
#define BATCH 4

using f32x4  = __attribute__((ext_vector_type(4))) float;
using bf16x8 = __attribute__((ext_vector_type(8))) __bf16;

__device__ __forceinline__ float silu_f(float x) { return x / (1.f + __expf(-x)); }
__device__ __forceinline__ float softplus_fast(float x) {
    return (x > 20.f) ? x : __logf(1.f + __expf(x));
}
// fp32 -> packed u32 (lo16<<16 | hi16), hi/lo = bf16 truncation split; x ~= hi+lo
__device__ __forceinline__ unsigned packsplit(float x) {
    unsigned hb = __float_as_uint(x) & 0xffff0000u;
    float r = x - __uint_as_float(hb);
    return (hb >> 16) | (__float_as_uint(r) & 0xffff0000u);
}
__device__ __forceinline__ float unpackf(unsigned p) {
    return __uint_as_float((p & 0xffffu) << 16) + __uint_as_float(p & 0xffff0000u);
}
// two packed elems -> (hi-pair, lo-pair) u32s for LDS bf16 rows (1 v_perm each)
__device__ __forceinline__ void unpack2(unsigned p0, unsigned p1, unsigned &h, unsigned &l) {
    h = __byte_perm(p0, p1, 0x5410);
    l = __byte_perm(p0, p1, 0x7632);
}
__device__ __forceinline__ void unpack8(const uint4 &q0, const uint4 &q1, uint4 &h, uint4 &l) {
    unpack2(q0.x, q0.y, h.x, l.x);
    unpack2(q0.z, q0.w, h.y, l.y);
    unpack2(q1.x, q1.y, h.z, l.z);
    unpack2(q1.z, q1.w, h.w, l.w);
}
// in-loop split for fp32 K-major staging (GEMM1 only)
__device__ __forceinline__ void split_pack2(float x0, float x1, unsigned &h, unsigned &l) {
    unsigned b0 = __float_as_uint(x0), b1 = __float_as_uint(x1);
    h = (b0 >> 16) | (b1 & 0xffff0000u);
    float l0 = x0 - __uint_as_float(b0 & 0xffff0000u);
    float l1 = x1 - __uint_as_float(b1 & 0xffff0000u);
    l = (__float_as_uint(l0) >> 16) | (__float_as_uint(l1) & 0xffff0000u);
}

enum { EPI_PACK = 0, EPI_SPLITUZ = 1, EPI_D34 = 2, EPI_F32 = 3 };

// ---------------- split-bf16 MFMA GEMM, packed-u32 operands ----------------
// Out[b,m,n] = sum_k A[b,m,k]*Wt[n,k] via ah*bh + ah*bl + al*bh.
// A: packed u32 [b][M][K] (or fp32 K-major sp/fq for A_F32KM). B: packed u32 [N][K].
// Staging unpacks via v_perm (cheap); producers paid the split once.
#define LDK 40
template<int EPI, bool A_F32KM, int NT>
__global__ __launch_bounds__(256)
void mfma_gemm(const float* __restrict__ Af0, const float* __restrict__ Af1,
               const unsigned* __restrict__ Apk, const unsigned* __restrict__ Bpk,
               const float* __restrict__ bias,
               float* __restrict__ O0, float* __restrict__ O1, float* __restrict__ O2,
               unsigned* __restrict__ Opk,
               int M, int N, int K, int kSplit, long strideAb, int nBlk)
{
    __shared__ __align__(16) unsigned short Ah[128][LDK], Al[128][LDK];
    __shared__ __align__(16) unsigned short Bh[NT * 16][LDK], Bl[NT * 16][LDK];
    const int mBlk = M / 128;
    // XCD-sticky swizzle: n-blocks of one (b,m) A-tile share bid%8 -> same XCD L2
    const int bid = blockIdx.x;
    const int r = bid & 7, q = bid >> 3;
    const int ni = q % nBlk;
    const int mg = (q / nBlk) * 8 + r;
    const int b = mg / mBlk, m_idx = mg - b * mBlk;
    const int n0 = ni * (NT * 16), m0 = m_idx * 128;
    const int tid  = threadIdx.x;
    const int lane = tid & 63;
    const int w    = tid >> 6;
    const int lrow = lane & 15;
    const int loct = lane >> 4;

    f32x4 acc[2][NT];
    #pragma unroll
    for (int i = 0; i < 2; ++i)
        #pragma unroll
        for (int j = 0; j < NT; ++j)
            acc[i][j] = (f32x4){0.f, 0.f, 0.f, 0.f};

    const int sOct = tid & 3, sRow = tid >> 2;
    float va[16];
    uint4 pa[2][2], pb[NT / 4][2];

    auto loadA = [&](int kk) {
        if (A_F32KM) {
            int m = tid & 127, half = tid >> 7;
            #pragma unroll
            for (int j = 0; j < 16; ++j) {
                int kg = kk + half * 16 + j;
                const float* Ap; int kl;
                if (kg < kSplit) { Ap = Af0; kl = kg; } else { Ap = Af1; kl = kg - kSplit; }
                va[j] = Ap[(long)b * strideAb + (long)kl * M + m0 + m];
            }
        } else {
            #pragma unroll
            for (int p = 0; p < 2; ++p) {
                const unsigned* g = Apk + (long)b * strideAb + (long)(m0 + sRow + p * 64) * K + kk + sOct * 8;
                pa[p][0] = *(const uint4*)g;
                pa[p][1] = *(const uint4*)(g + 4);
            }
        }
    };
    auto loadB = [&](int kk) {
        #pragma unroll
        for (int p = 0; p < NT / 4; ++p) {
            int ng = n0 + sRow + p * 64;
            if (EPI == EPI_D34 && ng >= N) {
                pb[p][0] = make_uint4(0, 0, 0, 0);
                pb[p][1] = make_uint4(0, 0, 0, 0);
            } else {
                const unsigned* g = Bpk + (long)ng * K + kk + sOct * 8;
                pb[p][0] = *(const uint4*)g;
                pb[p][1] = *(const uint4*)(g + 4);
            }
        }
    };
    auto storeAB = [&]() {
        if (A_F32KM) {
            int m = tid & 127, half = tid >> 7;
            #pragma unroll
            for (int o = 0; o < 2; ++o) {
                uint4 h, l;
                split_pack2(va[o*8+0], va[o*8+1], h.x, l.x);
                split_pack2(va[o*8+2], va[o*8+3], h.y, l.y);
                split_pack2(va[o*8+4], va[o*8+5], h.z, l.z);
                split_pack2(va[o*8+6], va[o*8+7], h.w, l.w);
                *(uint4*)&Ah[m][half*16 + o*8] = h;
                *(uint4*)&Al[m][half*16 + o*8] = l;
            }
        } else {
            #pragma unroll
            for (int p = 0; p < 2; ++p) {
                uint4 h, l;
                unpack8(pa[p][0], pa[p][1], h, l);
                *(uint4*)&Ah[sRow + p*64][sOct*8] = h;
                *(uint4*)&Al[sRow + p*64][sOct*8] = l;
            }
        }
        #pragma unroll
        for (int p = 0; p < NT / 4; ++p) {
            uint4 h, l;
            unpack8(pb[p][0], pb[p][1], h, l);
            *(uint4*)&Bh[sRow + p*64][sOct*8] = h;
            *(uint4*)&Bl[sRow + p*64][sOct*8] = l;
        }
    };

    loadA(0); loadB(0);
    for (int kk = 0; kk < K; kk += 32) {
        storeAB();
        __syncthreads();
        if (kk + 32 < K) { loadA(kk + 32); loadB(kk + 32); }   // in flight during MFMA
        bf16x8 ah[2], al2[2], bh[NT], bl2[NT];
        #pragma unroll
        for (int mt = 0; mt < 2; ++mt) {
            ah[mt]  = *(const bf16x8*)&Ah[w*32 + mt*16 + lrow][loct*8];
            al2[mt] = *(const bf16x8*)&Al[w*32 + mt*16 + lrow][loct*8];
        }
        #pragma unroll
        for (int nt = 0; nt < NT; ++nt) {
            bh[nt]  = *(const bf16x8*)&Bh[nt*16 + lrow][loct*8];
            bl2[nt] = *(const bf16x8*)&Bl[nt*16 + lrow][loct*8];
        }
        #pragma unroll
        for (int mt = 0; mt < 2; ++mt)
            #pragma unroll
            for (int nt = 0; nt < NT; ++nt) {
                acc[mt][nt] = __builtin_amdgcn_mfma_f32_16x16x32_bf16(ah[mt],  bh[nt],  acc[mt][nt], 0, 0, 0);
                acc[mt][nt] = __builtin_amdgcn_mfma_f32_16x16x32_bf16(ah[mt],  bl2[nt], acc[mt][nt], 0, 0, 0);
                acc[mt][nt] = __builtin_amdgcn_mfma_f32_16x16x32_bf16(al2[mt], bh[nt],  acc[mt][nt], 0, 0, 0);
            }
        __syncthreads();
    }
    // ---- epilogue: C/D col=lane&15, row=(lane>>4)*4+reg ----
    #pragma unroll
    for (int mt = 0; mt < 2; ++mt) {
        #pragma unroll
        for (int r4 = 0; r4 < 4; ++r4) {
            int m = m0 + w * 32 + mt * 16 + loct * 4 + r4;
            long rowb = (long)b * M + m;
            #pragma unroll
            for (int nt = 0; nt < NT; ++nt) {
                int n = n0 + nt * 16 + lrow;
                float v = acc[mt][nt][r4];
                if (EPI == EPI_PACK) {
                    v += bias[n];
                    Opk[rowb * N + n] = packsplit(v);
                } else if (EPI == EPI_SPLITUZ) {
                    if (n < DIN) O0[rowb * DIN + n] = v;
                    else         O1[rowb * DIN + (n - DIN)] = v;
                } else if (EPI == EPI_D34) {
                    if (n < DIN)            O0[rowb * DIN + n] = softplus_fast(v + bias[n]);
                    else if (n < DIN + 16)  O1[rowb * 16 + (n - DIN)] = v;
                    else if (n < DIN + 32)  O2[rowb * 16 + (n - DIN - 16)] = v;
                } else {  // EPI_F32
                    O0[rowb * N + n] = v;
                }
            }
        }
    }
}

// ---------------- weight fp32 -> packed split u32 ----------------
__global__ __launch_bounds__(256)
void pack_weight(const float* __restrict__ W, unsigned* __restrict__ Wpk, int n)
{
    int i = blockIdx.x * 256 + threadIdx.x;
    if (i < n) Wpk[i] = packsplit(W[i]);
}

// ---------------- Wcomb[544][512] packed: rows<512 = Wdt@Wx[:16]; 512.. = Wx[16:48] ----
__global__ __launch_bounds__(256)
void wcomb_kernel(const float* __restrict__ Wdt, const float* __restrict__ Wx,
                  unsigned* __restrict__ Wc)
{
    int idx = blockIdx.x * 256 + threadIdx.x;   // n*512 + k, n < 544
    int n = idx >> 9, k = idx & 511;
    float acc;
    if (n < DIN) {
        acc = 0.f;
        #pragma unroll
        for (int r = 0; r < DTR; ++r)
            acc += Wdt[n * DTR + r] * Wx[r * DIN + k];
    } else {
        acc = Wx[(DTR + (n - DIN)) * DIN + k];
    }
    Wc[idx] = packsplit(acc);
}

// ---------------- depthwise causal conv (k=4) + silu -> packed u ----------------
__global__ __launch_bounds__(256)
void conv_silu_kernel(const float* __restrict__ u_pre, const float* __restrict__ cw,
                      const float* __restrict__ cb, unsigned* __restrict__ upk)
{
    long idx = (long)blockIdx.x * blockDim.x + threadIdx.x;
    int d = (int)(idx % DIN);
    long bl = idx / DIN;
    int l = (int)(bl % L);
    long brow = bl - l;
    float v = cb[d];
    #pragma unroll
    for (int j = 0; j < 4; ++j) {
        int li = l - 3 + j;
        if (li >= 0) v += u_pre[(brow + li) * DIN + d] * cw[d * 4 + j];
    }
    upk[idx] = packsplit(silu_f(v));
}

// ---------------- chunked parallel selective scan, d-per-lane ----------------
#define NC 128
#define LC (L / NC)

__global__ __launch_bounds__(256)
void scan_phase1(const float* __restrict__ delta, const unsigned* __restrict__ upk,
                 const float* __restrict__ Bm, const float* __restrict__ A_log,
                 float* __restrict__ Asum, float* __restrict__ Xsum)
{
    __shared__ float sB[LC][DSTATE];
    const int gd = blockIdx.x & 1;
    const int c  = (blockIdx.x >> 1) & (NC - 1);
    const int b  = blockIdx.x >> 8;
    const int d  = gd * 256 + threadIdx.x;
    const int t0 = c * LC;
    float Arow[DSTATE];
    #pragma unroll
    for (int q = 0; q < 4; ++q) {
        float4 v = *(const float4*)&A_log[d * DSTATE + q * 4];
        Arow[q * 4 + 0] = -__expf(v.x);
        Arow[q * 4 + 1] = -__expf(v.y);
        Arow[q * 4 + 2] = -__expf(v.z);
        Arow[q * 4 + 3] = -__expf(v.w);
    }
    for (int i = threadIdx.x; i < LC * DSTATE; i += 256)
        sB[i >> 4][i & 15] = Bm[((long)b * L + t0 + (i >> 4)) * DSTATE + (i & 15)];
    __syncthreads();
    float P[DSTATE], X[DSTATE];
    #pragma unroll
    for (int s = 0; s < DSTATE; ++s) { P[s] = 1.f; X[s] = 0.f; }
    for (int t = 0; t < LC; ++t) {
        long gidx = ((long)b * L + t0 + t) * DIN + d;
        float dlt = delta[gidx];
        float du  = dlt * unpackf(upk[gidx]);
        #pragma unroll
        for (int s = 0; s < DSTATE; ++s) {
            float a = __expf(dlt * Arow[s]);
            P[s] *= a;
            X[s] = a * X[s] + du * sB[t][s];
        }
    }
    long o = (((long)b * NC + c) * DIN + d) * DSTATE;
    #pragma unroll
    for (int q = 0; q < 4; ++q) {
        *(float4*)&Asum[o + q * 4] = make_float4(P[q*4], P[q*4+1], P[q*4+2], P[q*4+3]);
        *(float4*)&Xsum[o + q * 4] = make_float4(X[q*4], X[q*4+1], X[q*4+2], X[q*4+3]);
    }
}

__global__ __launch_bounds__(256)
void scan_phase2(const float* __restrict__ Asum, float* __restrict__ Xsum)
{
    int lane = blockIdx.x * 256 + threadIdx.x;
    int b = lane / (DIN * DSTATE);
    int rem = lane % (DIN * DSTATE);
    float h = 0.f;
    for (int c = 0; c < NC; ++c) {
        long idx = ((long)b * NC + c) * (DIN * DSTATE) + rem;
        float A = Asum[idx], X = Xsum[idx];
        Xsum[idx] = h;
        h = A * h + X;
    }
}

__global__ __launch_bounds__(256)
void scan_phase3(const float* __restrict__ delta, const unsigned* __restrict__ upk,
                 const float* __restrict__ Bm, const float* __restrict__ Cm,
                 const float* __restrict__ z, const float* __restrict__ A_log,
                 const float* __restrict__ Dp, const float* __restrict__ Hinit,
                 unsigned* __restrict__ y2pk)
{
    __shared__ float sB[LC][DSTATE], sC[LC][DSTATE];
    const int gd = blockIdx.x & 1;
    const int c  = (blockIdx.x >> 1) & (NC - 1);
    const int b  = blockIdx.x >> 8;
    const int d  = gd * 256 + threadIdx.x;
    const int t0 = c * LC;
    float Arow[DSTATE];
    #pragma unroll
    for (int q = 0; q < 4; ++q) {
        float4 v = *(const float4*)&A_log[d * DSTATE + q * 4];
        Arow[q * 4 + 0] = -__expf(v.x);
        Arow[q * 4 + 1] = -__expf(v.y);
        Arow[q * 4 + 2] = -__expf(v.z);
        Arow[q * 4 + 3] = -__expf(v.w);
    }
    for (int i = threadIdx.x; i < LC * DSTATE; i += 256) {
        long gidx = ((long)b * L + t0 + (i >> 4)) * DSTATE + (i & 15);
        sB[i >> 4][i & 15] = Bm[gidx];
        sC[i >> 4][i & 15] = Cm[gidx];
    }
    float h[DSTATE];
    {
        long o = (((long)b * NC + c) * DIN + d) * DSTATE;
        #pragma unroll
        for (int q = 0; q < 4; ++q) {
            float4 v = *(const float4*)&Hinit[o + q * 4];
            h[q * 4 + 0] = v.x; h[q * 4 + 1] = v.y;
            h[q * 4 + 2] = v.z; h[q * 4 + 3] = v.w;
        }
    }
    const float Dval = Dp[d];
    __syncthreads();
    for (int t = 0; t < LC; ++t) {
        long gidx = ((long)b * L + t0 + t) * DIN + d;
        float dlt = delta[gidx];
        float uu  = unpackf(upk[gidx]);
        float zz  = z[gidx];
        float du  = dlt * uu;
        float y = 0.f;
        #pragma unroll
        for (int s = 0; s < DSTATE; ++s) {
            float a = __expf(dlt * Arow[s]);
            h[s] = h[s] * a + du * sB[t][s];
            y += h[s] * sC[t][s];
        }
        y2pk[gidx] = packsplit((y + uu * Dval) * silu_f(zz));
    }
}

// ---------------- LayerNorm over C + transpose to (B,C,L) ----------------
__global__ __launch_bounds__(256)
void ln_kernel(const float* __restrict__ X, const float* __restrict__ gamma,
               const float* __restrict__ beta, float* __restrict__ out)
{
    __shared__ float tile[32][257];
    __shared__ float sMu[32], sRs[32];
    const int l0 = blockIdx.x * 32;
    const int b  = blockIdx.y;
    const int tid = threadIdx.x;
    for (int i = tid; i < 32 * 256; i += 256) {
        int l = i >> 8, c = i & 255;
        tile[l][c] = X[((long)b * L + l0 + l) * CDIM + c];
    }
    __syncthreads();
    {
        int l = tid >> 3, sub = tid & 7;
        float s1 = 0.f, s2 = 0.f;
        for (int c = sub * 32; c < sub * 32 + 32; ++c) {
            float v = tile[l][c];
            s1 += v; s2 += v * v;
        }
        s1 += __shfl_xor(s1, 1); s2 += __shfl_xor(s2, 1);
        s1 += __shfl_xor(s1, 2); s2 += __shfl_xor(s2, 2);
        s1 += __shfl_xor(s1, 4); s2 += __shfl_xor(s2, 4);
        if (sub == 0) {
            float mu = s1 * (1.f / 256.f);
            float var = s2 * (1.f / 256.f) - mu * mu;
            sMu[l] = mu;
            sRs[l] = rsqrtf(var + 1e-5f);
        }
    }
    __syncthreads();
    for (int i = tid; i < 32 * 256; i += 256) {
        int ll = i & 31, c = i >> 5;
        float v = (tile[ll][c] - sMu[ll]) * sRs[ll] * gamma[c] + beta[c];
        out[((long)b * CDIM + c) * L + l0 + ll] = v;
    }
}

extern "C" void kernel_launch(void* const* d_in, const int* in_sizes, int n_in,
                              void* d_out, int out_size, void* d_ws, size_t ws_size,
                              hipStream_t stream)
{
    const float* sp   = (const float*)d_in[0];
    const float* fq   = (const float*)d_in[1];
    const float* Wp   = (const float*)d_in[2];
    const float* bp   = (const float*)d_in[3];
    const float* Win  = (const float*)d_in[4];
    const float* cw   = (const float*)d_in[5];
    const float* cb   = (const float*)d_in[6];
    const float* Wx   = (const float*)d_in[7];
    const float* Wdt  = (const float*)d_in[8];
    const float* bdt  = (const float*)d_in[9];
    const float* Alog = (const float*)d_in[10];
    const float* Dp   = (const float*)d_in[11];
    const float* Wout = (const float*)d_in[12];
    const float* gam  = (const float*)d_in[13];
    const float* bet  = (const float*)d_in[14];
    float* out = (float*)d_out;
    float* ws  = (float*)d_ws;

    const size_t NLD = (size_t)BATCH * L * DIN;   // 8.39M
    const size_t NLC = (size_t)BATCH * L * CDIM;  // 4.19M

    size_t off = 0;
    float* u_pre = ws + off; off += NLD;          // pre-conv u -> later delta
    float* zb    = ws + off; off += NLD;
    unsigned* upk  = (unsigned*)(ws + off); off += NLD;   // packed u (split pair per elem)
    unsigned* y2pk = (unsigned*)(ws + off); off += NLD;   // packed y2
    unsigned* xppk = (unsigned*)(ws + off); off += NLC;   // packed x_proj
    float* xmix  = ws + off; off += NLC;
    unsigned* wp_pk  = (unsigned*)(ws + off); off += (size_t)CDIM * 2 * CDIM;   // 131072
    unsigned* win_pk = (unsigned*)(ws + off); off += (size_t)2 * DIN * CDIM;    // 262144
    unsigned* wo_pk  = (unsigned*)(ws + off); off += (size_t)CDIM * DIN;        // 131072
    unsigned* wc_pk  = (unsigned*)(ws + off); off += (size_t)544 * DIN;         // 278528
    float* Bmb   = ws + off; off += (size_t)BATCH * L * DSTATE;
    float* Cmb   = ws + off; off += (size_t)BATCH * L * DSTATE;
    float* Asum  = ws + off; off += (size_t)BATCH * NC * DIN * DSTATE;
    float* Xsum  = ws + off; off += (size_t)BATCH * NC * DIN * DSTATE;

    dim3 blk(256);
    pack_weight<<<dim3(512), blk, 0, stream>>>(Wp, wp_pk, 131072);
    pack_weight<<<dim3(1024), blk, 0, stream>>>(Win, win_pk, 262144);
    pack_weight<<<dim3(512), blk, 0, stream>>>(Wout, wo_pk, 131072);
    wcomb_kernel<<<dim3(544 * 512 / 256), blk, 0, stream>>>(Wdt, Wx, wc_pk);

    // GEMM1: x_proj(packed) = x_cat @ Wp^T + bp  (A fp32 K-major from sp/fq)
    mfma_gemm<EPI_PACK, true, 4><<<dim3(BATCH * (L/128) * 4), blk, 0, stream>>>(
        sp, fq, nullptr, wp_pk, bp, nullptr, nullptr, nullptr, xppk,
        L, CDIM, 2 * CDIM, CDIM, (long)CDIM * L, 4);
    // GEMM2: xz = x_proj @ Win^T -> u_pre / zb (fp32)
    mfma_gemm<EPI_SPLITUZ, false, 4><<<dim3(BATCH * (L/128) * 16), blk, 0, stream>>>(
        nullptr, nullptr, xppk, win_pk, nullptr, u_pre, zb, nullptr, nullptr,
        L, 2 * DIN, CDIM, 1 << 30, (long)L * CDIM, 16);
    conv_silu_kernel<<<dim3((int)(NLD / 256)), blk, 0, stream>>>(u_pre, cw, cb, upk);
    // D34: [delta | Bm | Cm] = u @ Wcomb^T, softplus on delta (into u_pre)
    mfma_gemm<EPI_D34, false, 4><<<dim3(BATCH * (L/128) * 9), blk, 0, stream>>>(
        nullptr, nullptr, upk, wc_pk, bdt, u_pre, Bmb, Cmb, nullptr,
        L, 544, DIN, 1 << 30, (long)L * DIN, 9);

    scan_phase1<<<dim3(BATCH * NC * 2), blk, 0, stream>>>(u_pre, upk, Bmb, Alog, Asum, Xsum);
    scan_phase2<<<dim3(BATCH * DIN * DSTATE / 256), blk, 0, stream>>>(Asum, Xsum);
    scan_phase3<<<dim3(BATCH * NC * 2), blk, 0, stream>>>(
        u_pre, upk, Bmb, Cmb, zb, Alog, Dp, Xsum, y2pk);

    // GEMM5: x_mixed = y2 @ Wout^T (fp32 out)
    mfma_gemm<EPI_F32, false, 4><<<dim3(BATCH * (L/128) * 4), blk, 0, stream>>>(
        nullptr, nullptr, y2pk, wo_pk, nullptr, xmix, nullptr, nullptr, nullptr,
        L, CDIM, DIN, 1 << 30, (long)L * DIN, 4);
    ln_kernel<<<dim3(L / 32, BATCH), blk, 0, stream>>>(xmix, gam, bet, out);
}

// Round 10
// 385.035 us; speedup vs baseline: 1.6274x; 1.0108x over previous
//
#include <hip/hip_runtime.h>
#include <math.h>

#define L 4096
#define CDIM 256
#define DIN 512
#define DSTATE 16
#define DTR 16
#define BATCH 4

using f32x4  = __attribute__((ext_vector_type(4))) float;
using bf16x8 = __attribute__((ext_vector_type(8))) __bf16;

__device__ __forceinline__ float silu_f(float x) { return x / (1.f + __expf(-x)); }
__device__ __forceinline__ float softplus_fast(float x) {
    return (x > 20.f) ? x : __logf(1.f + __expf(x));
}
// fp32 -> packed u32 (lo16<<16 | hi16), hi/lo = bf16 truncation split; x ~= hi+lo
__device__ __forceinline__ unsigned packsplit(float x) {
    unsigned hb = __float_as_uint(x) & 0xffff0000u;
    float r = x - __uint_as_float(hb);
    return (hb >> 16) | (__float_as_uint(r) & 0xffff0000u);
}
__device__ __forceinline__ float unpackf(unsigned p) {
    return __uint_as_float((p & 0xffffu) << 16) + __uint_as_float(p & 0xffff0000u);
}
__device__ __forceinline__ void unpack2(unsigned p0, unsigned p1, unsigned &h, unsigned &l) {
    h = __byte_perm(p0, p1, 0x5410);
    l = __byte_perm(p0, p1, 0x7632);
}
__device__ __forceinline__ void unpack8(const uint4 &q0, const uint4 &q1, uint4 &h, uint4 &l) {
    unpack2(q0.x, q0.y, h.x, l.x);
    unpack2(q0.z, q0.w, h.y, l.y);
    unpack2(q1.x, q1.y, h.z, l.z);
    unpack2(q1.z, q1.w, h.w, l.w);
}
// in-loop split for fp32 K-major staging (GEMM1 only)
__device__ __forceinline__ void split_pack2(float x0, float x1, unsigned &h, unsigned &l) {
    unsigned b0 = __float_as_uint(x0), b1 = __float_as_uint(x1);
    h = (b0 >> 16) | (b1 & 0xffff0000u);
    float l0 = x0 - __uint_as_float(b0 & 0xffff0000u);
    float l1 = x1 - __uint_as_float(b1 & 0xffff0000u);
    l = (__float_as_uint(l0) >> 16) | (__float_as_uint(l1) & 0xffff0000u);
}

enum { EPI_PACK = 0, EPI_SPLITUZ = 1, EPI_D34 = 2, EPI_F32 = 3 };

// ---------------- split-bf16 MFMA GEMM, packed operands, 4x4 register blocking ----
// Out[b,m,n] = sum_k A[b,m,k]*Wt[n,k] via ah*bh + ah*bl + al*bh.
// Block tile 128 x (2*NT*16); 4 waves in 2x2; wave tile = (MT*16) x (NT*16).
// MT=4,NT=4: 48 MFMA per 16 ds_read_b128 (2x the FLOP/LDS-byte of 2x4).
#define LDK 40
template<int EPI, bool A_F32KM, int MT, int NT>
__global__ __launch_bounds__(256)
void mfma_gemm(const float* __restrict__ Af0, const float* __restrict__ Af1,
               const unsigned* __restrict__ Apk, const unsigned* __restrict__ Bpk,
               const float* __restrict__ bias,
               float* __restrict__ O0, float* __restrict__ O1, float* __restrict__ O2,
               unsigned* __restrict__ Opk,
               int M, int N, int K, int kSplit, long strideAb, int nBlk)
{
    constexpr int BN = 2 * NT * 16;
    constexpr int BSEG = BN / 64;      // B row segments staged per thread (1 or 2)
    __shared__ __align__(16) unsigned short Ah[128][LDK], Al[128][LDK];
    __shared__ __align__(16) unsigned short Bh[BN][LDK],  Bl[BN][LDK];
    const int mBlk = M / 128;
    // XCD-sticky swizzle: n-blocks of one (b,m) A-tile share bid%8 -> same XCD L2
    const int bid = blockIdx.x;
    const int r = bid & 7, q = bid >> 3;
    const int ni = q % nBlk;
    const int mg = (q / nBlk) * 8 + r;
    const int b = mg / mBlk, m_idx = mg - b * mBlk;
    const int n0 = ni * BN, m0 = m_idx * 128;
    const int tid  = threadIdx.x;
    const int lane = tid & 63;
    const int w    = tid >> 6;
    const int wr   = w >> 1, wc = w & 1;
    const int lrow = lane & 15;
    const int loct = lane >> 4;

    f32x4 acc[MT][NT];
    #pragma unroll
    for (int i = 0; i < MT; ++i)
        #pragma unroll
        for (int j = 0; j < NT; ++j)
            acc[i][j] = (f32x4){0.f, 0.f, 0.f, 0.f};

    const int sOct = tid & 3, sRow = tid >> 2;
    float va[16];
    uint4 pa[2][2], pb[BSEG][2];

    auto loadA = [&](int kk) {
        if (A_F32KM) {
            int m = tid & 127, half = tid >> 7;
            #pragma unroll
            for (int j = 0; j < 16; ++j) {
                int kg = kk + half * 16 + j;
                const float* Ap; int kl;
                if (kg < kSplit) { Ap = Af0; kl = kg; } else { Ap = Af1; kl = kg - kSplit; }
                va[j] = Ap[(long)b * strideAb + (long)kl * M + m0 + m];
            }
        } else {
            #pragma unroll
            for (int p = 0; p < 2; ++p) {
                const unsigned* g = Apk + (long)b * strideAb + (long)(m0 + sRow + p * 64) * K + kk + sOct * 8;
                pa[p][0] = *(const uint4*)g;
                pa[p][1] = *(const uint4*)(g + 4);
            }
        }
    };
    auto loadB = [&](int kk) {
        #pragma unroll
        for (int p = 0; p < BSEG; ++p) {
            int ng = n0 + sRow + p * 64;
            if (EPI == EPI_D34 && ng >= N) {
                pb[p][0] = make_uint4(0, 0, 0, 0);
                pb[p][1] = make_uint4(0, 0, 0, 0);
            } else {
                const unsigned* g = Bpk + (long)ng * K + kk + sOct * 8;
                pb[p][0] = *(const uint4*)g;
                pb[p][1] = *(const uint4*)(g + 4);
            }
        }
    };
    auto storeAB = [&]() {
        if (A_F32KM) {
            int m = tid & 127, half = tid >> 7;
            #pragma unroll
            for (int o = 0; o < 2; ++o) {
                uint4 h, l;
                split_pack2(va[o*8+0], va[o*8+1], h.x, l.x);
                split_pack2(va[o*8+2], va[o*8+3], h.y, l.y);
                split_pack2(va[o*8+4], va[o*8+5], h.z, l.z);
                split_pack2(va[o*8+6], va[o*8+7], h.w, l.w);
                *(uint4*)&Ah[m][half*16 + o*8] = h;
                *(uint4*)&Al[m][half*16 + o*8] = l;
            }
        } else {
            #pragma unroll
            for (int p = 0; p < 2; ++p) {
                uint4 h, l;
                unpack8(pa[p][0], pa[p][1], h, l);
                *(uint4*)&Ah[sRow + p*64][sOct*8] = h;
                *(uint4*)&Al[sRow + p*64][sOct*8] = l;
            }
        }
        #pragma unroll
        for (int p = 0; p < BSEG; ++p) {
            uint4 h, l;
            unpack8(pb[p][0], pb[p][1], h, l);
            *(uint4*)&Bh[sRow + p*64][sOct*8] = h;
            *(uint4*)&Bl[sRow + p*64][sOct*8] = l;
        }
    };

    loadA(0); loadB(0);
    for (int kk = 0; kk < K; kk += 32) {
        storeAB();
        __syncthreads();
        if (kk + 32 < K) { loadA(kk + 32); loadB(kk + 32); }   // in flight during MFMA
        bf16x8 bh[NT], bl2[NT];
        #pragma unroll
        for (int nt = 0; nt < NT; ++nt) {
            bh[nt]  = *(const bf16x8*)&Bh[wc*NT*16 + nt*16 + lrow][loct*8];
            bl2[nt] = *(const bf16x8*)&Bl[wc*NT*16 + nt*16 + lrow][loct*8];
        }
        #pragma unroll
        for (int mt = 0; mt < MT; ++mt) {
            bf16x8 ah  = *(const bf16x8*)&Ah[wr*MT*16 + mt*16 + lrow][loct*8];
            bf16x8 al2 = *(const bf16x8*)&Al[wr*MT*16 + mt*16 + lrow][loct*8];
            #pragma unroll
            for (int nt = 0; nt < NT; ++nt) {
                acc[mt][nt] = __builtin_amdgcn_mfma_f32_16x16x32_bf16(ah,  bh[nt],  acc[mt][nt], 0, 0, 0);
                acc[mt][nt] = __builtin_amdgcn_mfma_f32_16x16x32_bf16(ah,  bl2[nt], acc[mt][nt], 0, 0, 0);
                acc[mt][nt] = __builtin_amdgcn_mfma_f32_16x16x32_bf16(al2, bh[nt],  acc[mt][nt], 0, 0, 0);
            }
        }
        __syncthreads();
    }
    // ---- epilogue: C/D col=lane&15, row=(lane>>4)*4+reg ----
    #pragma unroll
    for (int mt = 0; mt < MT; ++mt) {
        #pragma unroll
        for (int r4 = 0; r4 < 4; ++r4) {
            int m = m0 + wr*MT*16 + mt * 16 + loct * 4 + r4;
            long rowb = (long)b * M + m;
            #pragma unroll
            for (int nt = 0; nt < NT; ++nt) {
                int n = n0 + wc*NT*16 + nt * 16 + lrow;
                float v = acc[mt][nt][r4];
                if (EPI == EPI_PACK) {
                    v += bias[n];
                    Opk[rowb * N + n] = packsplit(v);
                } else if (EPI == EPI_SPLITUZ) {
                    if (n < DIN) O0[rowb * DIN + n] = v;
                    else         O1[rowb * DIN + (n - DIN)] = v;
                } else if (EPI == EPI_D34) {
                    if (n < DIN)            O0[rowb * DIN + n] = softplus_fast(v + bias[n]);
                    else if (n < DIN + 16)  O1[rowb * 16 + (n - DIN)] = v;
                    else if (n < DIN + 32)  O2[rowb * 16 + (n - DIN - 16)] = v;
                } else {  // EPI_F32
                    O0[rowb * N + n] = v;
                }
            }
        }
    }
}

// ---------------- weight fp32 -> packed split u32 ----------------
__global__ __launch_bounds__(256)
void pack_weight(const float* __restrict__ W, unsigned* __restrict__ Wpk, int n)
{
    int i = blockIdx.x * 256 + threadIdx.x;
    if (i < n) Wpk[i] = packsplit(W[i]);
}

// ---------------- Wcomb[544][512] packed: rows<512 = Wdt@Wx[:16]; 512.. = Wx[16:48] ----
__global__ __launch_bounds__(256)
void wcomb_kernel(const float* __restrict__ Wdt, const float* __restrict__ Wx,
                  unsigned* __restrict__ Wc)
{
    int idx = blockIdx.x * 256 + threadIdx.x;   // n*512 + k, n < 544
    int n = idx >> 9, k = idx & 511;
    float acc;
    if (n < DIN) {
        acc = 0.f;
        #pragma unroll
        for (int r = 0; r < DTR; ++r)
            acc += Wdt[n * DTR + r] * Wx[r * DIN + k];
    } else {
        acc = Wx[(DTR + (n - DIN)) * DIN + k];
    }
    Wc[idx] = packsplit(acc);
}

// ---------------- depthwise causal conv (k=4) + silu -> packed u ----------------
__global__ __launch_bounds__(256)
void conv_silu_kernel(const float* __restrict__ u_pre, const float* __restrict__ cw,
                      const float* __restrict__ cb, unsigned* __restrict__ upk)
{
    long idx = (long)blockIdx.x * blockDim.x + threadIdx.x;
    int d = (int)(idx % DIN);
    long bl = idx / DIN;
    int l = (int)(bl % L);
    long brow = bl - l;
    float v = cb[d];
    #pragma unroll
    for (int j = 0; j < 4; ++j) {
        int li = l - 3 + j;
        if (li >= 0) v += u_pre[(brow + li) * DIN + d] * cw[d * 4 + j];
    }
    upk[idx] = packsplit(silu_f(v));
}

// ---------------- chunked parallel selective scan, d-per-lane ----------------
#define NC 128
#define LC (L / NC)

__global__ __launch_bounds__(256)
void scan_phase1(const float* __restrict__ delta, const unsigned* __restrict__ upk,
                 const float* __restrict__ Bm, const float* __restrict__ A_log,
                 float* __restrict__ Asum, float* __restrict__ Xsum)
{
    __shared__ float sB[LC][DSTATE];
    const int gd = blockIdx.x & 1;
    const int c  = (blockIdx.x >> 1) & (NC - 1);
    const int b  = blockIdx.x >> 8;
    const int d  = gd * 256 + threadIdx.x;
    const int t0 = c * LC;
    float Arow[DSTATE];
    #pragma unroll
    for (int q = 0; q < 4; ++q) {
        float4 v = *(const float4*)&A_log[d * DSTATE + q * 4];
        Arow[q * 4 + 0] = -__expf(v.x);
        Arow[q * 4 + 1] = -__expf(v.y);
        Arow[q * 4 + 2] = -__expf(v.z);
        Arow[q * 4 + 3] = -__expf(v.w);
    }
    for (int i = threadIdx.x; i < LC * DSTATE; i += 256)
        sB[i >> 4][i & 15] = Bm[((long)b * L + t0 + (i >> 4)) * DSTATE + (i & 15)];
    __syncthreads();
    float P[DSTATE], X[DSTATE];
    #pragma unroll
    for (int s = 0; s < DSTATE; ++s) { P[s] = 1.f; X[s] = 0.f; }
    for (int t = 0; t < LC; ++t) {
        long gidx = ((long)b * L + t0 + t) * DIN + d;
        float dlt = delta[gidx];
        float du  = dlt * unpackf(upk[gidx]);
        #pragma unroll
        for (int s = 0; s < DSTATE; ++s) {
            float a = __expf(dlt * Arow[s]);
            P[s] *= a;
            X[s] = a * X[s] + du * sB[t][s];
        }
    }
    long o = (((long)b * NC + c) * DIN + d) * DSTATE;
    #pragma unroll
    for (int q = 0; q < 4; ++q) {
        *(float4*)&Asum[o + q * 4] = make_float4(P[q*4], P[q*4+1], P[q*4+2], P[q*4+3]);
        *(float4*)&Xsum[o + q * 4] = make_float4(X[q*4], X[q*4+1], X[q*4+2], X[q*4+3]);
    }
}

__global__ __launch_bounds__(256)
void scan_phase2(const float* __restrict__ Asum, float* __restrict__ Xsum)
{
    int lane = blockIdx.x * 256 + threadIdx.x;
    int b = lane / (DIN * DSTATE);
    int rem = lane % (DIN * DSTATE);
    float h = 0.f;
    for (int c = 0; c < NC; ++c) {
        long idx = ((long)b * NC + c) * (DIN * DSTATE) + rem;
        float A = Asum[idx], X = Xsum[idx];
        Xsum[idx] = h;
        h = A * h + X;
    }
}

__global__ __launch_bounds__(256)
void scan_phase3(const float* __restrict__ delta, const unsigned* __restrict__ upk,
                 const float* __restrict__ Bm, const float* __restrict__ Cm,
                 const float* __restrict__ z, const float* __restrict__ A_log,
                 const float* __restrict__ Dp, const float* __restrict__ Hinit,
                 unsigned* __restrict__ y2pk)
{
    __shared__ float sB[LC][DSTATE], sC[LC][DSTATE];
    const int gd = blockIdx.x & 1;
    const int c  = (blockIdx.x >> 1) & (NC - 1);
    const int b  = blockIdx.x >> 8;
    const int d  = gd * 256 + threadIdx.x;
    const int t0 = c * LC;
    float Arow[DSTATE];
    #pragma unroll
    for (int q = 0; q < 4; ++q) {
        float4 v = *(const float4*)&A_log[d * DSTATE + q * 4];
        Arow[q * 4 + 0] = -__expf(v.x);
        Arow[q * 4 + 1] = -__expf(v.y);
        Arow[q * 4 + 2] = -__expf(v.z);
        Arow[q * 4 + 3] = -__expf(v.w);
    }
    for (int i = threadIdx.x; i < LC * DSTATE; i += 256) {
        long gidx = ((long)b * L + t0 + (i >> 4)) * DSTATE + (i & 15);
        sB[i >> 4][i & 15] = Bm[gidx];
        sC[i >> 4][i & 15] = Cm[gidx];
    }
    float h[DSTATE];
    {
        long o = (((long)b * NC + c) * DIN + d) * DSTATE;
        #pragma unroll
        for (int q = 0; q < 4; ++q) {
            float4 v = *(const float4*)&Hinit[o + q * 4];
            h[q * 4 + 0] = v.x; h[q * 4 + 1] = v.y;
            h[q * 4 + 2] = v.z; h[q * 4 + 3] = v.w;
        }
    }
    const float Dval = Dp[d];
    __syncthreads();
    for (int t = 0; t < LC; ++t) {
        long gidx = ((long)b * L + t0 + t) * DIN + d;
        float dlt = delta[gidx];
        float uu  = unpackf(upk[gidx]);
        float zz  = z[gidx];
        float du  = dlt * uu;
        float y = 0.f;
        #pragma unroll
        for (int s = 0; s < DSTATE; ++s) {
            float a = __expf(dlt * Arow[s]);
            h[s] = h[s] * a + du * sB[t][s];
            y += h[s] * sC[t][s];
        }
        y2pk[gidx] = packsplit((y + uu * Dval) * silu_f(zz));
    }
}

// ---------------- LayerNorm over C + transpose to (B,C,L) ----------------
__global__ __launch_bounds__(256)
void ln_kernel(const float* __restrict__ X, const float* __restrict__ gamma,
               const float* __restrict__ beta, float* __restrict__ out)
{
    __shared__ float tile[32][257];
    __shared__ float sMu[32], sRs[32];
    const int l0 = blockIdx.x * 32;
    const int b  = blockIdx.y;
    const int tid = threadIdx.x;
    for (int i = tid; i < 32 * 256; i += 256) {
        int l = i >> 8, c = i & 255;
        tile[l][c] = X[((long)b * L + l0 + l) * CDIM + c];
    }
    __syncthreads();
    {
        int l = tid >> 3, sub = tid & 7;
        float s1 = 0.f, s2 = 0.f;
        for (int c = sub * 32; c < sub * 32 + 32; ++c) {
            float v = tile[l][c];
            s1 += v; s2 += v * v;
        }
        s1 += __shfl_xor(s1, 1); s2 += __shfl_xor(s2, 1);
        s1 += __shfl_xor(s1, 2); s2 += __shfl_xor(s2, 2);
        s1 += __shfl_xor(s1, 4); s2 += __shfl_xor(s2, 4);
        if (sub == 0) {
            float mu = s1 * (1.f / 256.f);
            float var = s2 * (1.f / 256.f) - mu * mu;
            sMu[l] = mu;
            sRs[l] = rsqrtf(var + 1e-5f);
        }
    }
    __syncthreads();
    for (int i = tid; i < 32 * 256; i += 256) {
        int ll = i & 31, c = i >> 5;
        float v = (tile[ll][c] - sMu[ll]) * sRs[ll] * gamma[c] + beta[c];
        out[((long)b * CDIM + c) * L + l0 + ll] = v;
    }
}

extern "C" void kernel_launch(void* const* d_in, const int* in_sizes, int n_in,
                              void* d_out, int out_size, void* d_ws, size_t ws_size,
                              hipStream_t stream)
{
    const float* sp   = (const float*)d_in[0];
    const float* fq   = (const float*)d_in[1];
    const float* Wp   = (const float*)d_in[2];
    const float* bp   = (const float*)d_in[3];
    const float* Win  = (const float*)d_in[4];
    const float* cw   = (const float*)d_in[5];
    const float* cb   = (const float*)d_in[6];
    const float* Wx   = (const float*)d_in[7];
    const float* Wdt  = (const float*)d_in[8];
    const float* bdt  = (const float*)d_in[9];
    const float* Alog = (const float*)d_in[10];
    const float* Dp   = (const float*)d_in[11];
    const float* Wout = (const float*)d_in[12];
    const float* gam  = (const float*)d_in[13];
    const float* bet  = (const float*)d_in[14];
    float* out = (float*)d_out;
    float* ws  = (float*)d_ws;

    const size_t NLD = (size_t)BATCH * L * DIN;   // 8.39M
    const size_t NLC = (size_t)BATCH * L * CDIM;  // 4.19M

    size_t off = 0;
    float* u_pre = ws + off; off += NLD;          // pre-conv u -> later delta
    float* zb    = ws + off; off += NLD;
    unsigned* upk  = (unsigned*)(ws + off); off += NLD;   // packed u (split pair per elem)
    unsigned* y2pk = (unsigned*)(ws + off); off += NLD;   // packed y2
    unsigned* xppk = (unsigned*)(ws + off); off += NLC;   // packed x_proj
    float* xmix  = ws + off; off += NLC;
    unsigned* wp_pk  = (unsigned*)(ws + off); off += (size_t)CDIM * 2 * CDIM;   // 131072
    unsigned* win_pk = (unsigned*)(ws + off); off += (size_t)2 * DIN * CDIM;    // 262144
    unsigned* wo_pk  = (unsigned*)(ws + off); off += (size_t)CDIM * DIN;        // 131072
    unsigned* wc_pk  = (unsigned*)(ws + off); off += (size_t)544 * DIN;         // 278528
    float* Bmb   = ws + off; off += (size_t)BATCH * L * DSTATE;
    float* Cmb   = ws + off; off += (size_t)BATCH * L * DSTATE;
    float* Asum  = ws + off; off += (size_t)BATCH * NC * DIN * DSTATE;
    float* Xsum  = ws + off; off += (size_t)BATCH * NC * DIN * DSTATE;

    dim3 blk(256);
    pack_weight<<<dim3(512), blk, 0, stream>>>(Wp, wp_pk, 131072);
    pack_weight<<<dim3(1024), blk, 0, stream>>>(Win, win_pk, 262144);
    pack_weight<<<dim3(512), blk, 0, stream>>>(Wout, wo_pk, 131072);
    wcomb_kernel<<<dim3(544 * 512 / 256), blk, 0, stream>>>(Wdt, Wx, wc_pk);

    // GEMM1: x_proj(packed) = x_cat @ Wp^T + bp  (A fp32 K-major; MT=4,NT=2 -> BN=64)
    mfma_gemm<EPI_PACK, true, 4, 2><<<dim3(BATCH * (L/128) * 4), blk, 0, stream>>>(
        sp, fq, nullptr, wp_pk, bp, nullptr, nullptr, nullptr, xppk,
        L, CDIM, 2 * CDIM, CDIM, (long)CDIM * L, 4);
    // GEMM2: xz = x_proj @ Win^T -> u_pre / zb (MT=4,NT=4 -> BN=128, nBlk=8)
    mfma_gemm<EPI_SPLITUZ, false, 4, 4><<<dim3(BATCH * (L/128) * 8), blk, 0, stream>>>(
        nullptr, nullptr, xppk, win_pk, nullptr, u_pre, zb, nullptr, nullptr,
        L, 2 * DIN, CDIM, 1 << 30, (long)L * CDIM, 8);
    conv_silu_kernel<<<dim3((int)(NLD / 256)), blk, 0, stream>>>(u_pre, cw, cb, upk);
    // D34: [delta | Bm | Cm] = u @ Wcomb^T (MT=4,NT=4, nBlk=5 with guard)
    mfma_gemm<EPI_D34, false, 4, 4><<<dim3(BATCH * (L/128) * 5), blk, 0, stream>>>(
        nullptr, nullptr, upk, wc_pk, bdt, u_pre, Bmb, Cmb, nullptr,
        L, 544, DIN, 1 << 30, (long)L * DIN, 5);

    scan_phase1<<<dim3(BATCH * NC * 2), blk, 0, stream>>>(u_pre, upk, Bmb, Alog, Asum, Xsum);
    scan_phase2<<<dim3(BATCH * DIN * DSTATE / 256), blk, 0, stream>>>(Asum, Xsum);
    scan_phase3<<<dim3(BATCH * NC * 2), blk, 0, stream>>>(
        u_pre, upk, Bmb, Cmb, zb, Alog, Dp, Xsum, y2pk);

    // GEMM5: x_mixed = y2 @ Wout^T (MT=4,NT=2 -> BN=64, nBlk=4)
    mfma_gemm<EPI_F32, false, 4, 2><<<dim3(BATCH * (L/128) * 4), blk, 0, stream>>>(
        nullptr, nullptr, y2pk, wo_pk, nullptr, xmix, nullptr, nullptr, nullptr,
        L, CDIM, DIN, 1 << 30, (long)L * DIN, 4);
    ln_kernel<<<dim3(L / 32, BATCH), blk, 0, stream>>>(xmix, gam, bet, out);
}

// Round 11
// 384.354 us; speedup vs baseline: 1.6303x; 1.0018x over previous
//
#include <hip/hip_runtime.h>
#include <hip/hip_fp16.h>
#include <math.h>

#define L 4096
#define CDIM 256
#define DIN 512
#define DSTATE 16
#define DTR 16
#define BATCH 4

using f32x4  = __attribute__((ext_vector_type(4))) float;
using bf16x8 = __attribute__((ext_vector_type(8))) __bf16;
using f16x8  = __attribute__((ext_vector_type(8))) _Float16;

__device__ __forceinline__ float silu_f(float x) { return x / (1.f + __expf(-x)); }
__device__ __forceinline__ float softplus_fast(float x) {
    return (x > 20.f) ? x : __logf(1.f + __expf(x));
}
// fp32 -> packed u32 (lo16<<16 | hi16), hi/lo = bf16 truncation split; x ~= hi+lo
__device__ __forceinline__ unsigned packsplit(float x) {
    unsigned hb = __float_as_uint(x) & 0xffff0000u;
    float r = x - __uint_as_float(hb);
    return (hb >> 16) | (__float_as_uint(r) & 0xffff0000u);
}
__device__ __forceinline__ float unpackf(unsigned p) {
    return __uint_as_float((p & 0xffffu) << 16) + __uint_as_float(p & 0xffff0000u);
}
__device__ __forceinline__ void unpack2(unsigned p0, unsigned p1, unsigned &h, unsigned &l) {
    h = __byte_perm(p0, p1, 0x5410);
    l = __byte_perm(p0, p1, 0x7632);
}
__device__ __forceinline__ void unpack8(const uint4 &q0, const uint4 &q1, uint4 &h, uint4 &l) {
    unpack2(q0.x, q0.y, h.x, l.x);
    unpack2(q0.z, q0.w, h.y, l.y);
    unpack2(q1.x, q1.y, h.z, l.z);
    unpack2(q1.z, q1.w, h.w, l.w);
}
// two fp32 -> one u32 holding two rn fp16
__device__ __forceinline__ unsigned pk2h(float a, float b) {
    __half2 h = __floats2half2_rn(a, b);
    return *reinterpret_cast<unsigned*>(&h);
}

#define LDK 40

// ================= single-plane fp16 MFMA GEMM (GEMM1/2/5) =================
// Out[b,m,n] = sum_k A*W. A fp16 row-major (or fp32 K-major for GEMM1).
// Block 128 x (2*NT*16); waves 2x2; wave tile (MT*16)x(NT*16). 1 MFMA/tile.
enum { HEPI_XP = 0, HEPI_UZ = 1, HEPI_F32 = 2 };
template<int EPI, bool A_F32KM, int MT, int NT>
__global__ __launch_bounds__(256)
void hgemm(const float* __restrict__ Af0, const float* __restrict__ Af1,
           const __half* __restrict__ Ah_g, const __half* __restrict__ Bh_g,
           const float* __restrict__ bias,
           float* __restrict__ O0, __half* __restrict__ Oh0, __half* __restrict__ Oh1,
           int M, int N, int K, int kSplit, long strideAb, int nBlk)
{
    constexpr int BN = 2 * NT * 16;
    constexpr int BSEG = BN / 64;
    __shared__ __align__(16) _Float16 Ah[128][LDK];
    __shared__ __align__(16) _Float16 Bh[BN][LDK];
    const int mBlk = M / 128;
    const int bid = blockIdx.x;
    const int r = bid & 7, q = bid >> 3;
    const int ni = q % nBlk;
    const int mg = (q / nBlk) * 8 + r;
    const int b = mg / mBlk, m_idx = mg - b * mBlk;
    const int n0 = ni * BN, m0 = m_idx * 128;
    const int tid  = threadIdx.x;
    const int lane = tid & 63;
    const int w    = tid >> 6;
    const int wr   = w >> 1, wc = w & 1;
    const int lrow = lane & 15;
    const int loct = lane >> 4;

    f32x4 acc[MT][NT];
    #pragma unroll
    for (int i = 0; i < MT; ++i)
        #pragma unroll
        for (int j = 0; j < NT; ++j)
            acc[i][j] = (f32x4){0.f, 0.f, 0.f, 0.f};

    const int sOct = tid & 3, sRow = tid >> 2;
    float va[16];
    uint4 pa[2], pb[BSEG];

    auto loadA = [&](int kk) {
        if (A_F32KM) {
            int m = tid & 127, half = tid >> 7;
            #pragma unroll
            for (int j = 0; j < 16; ++j) {
                int kg = kk + half * 16 + j;
                const float* Ap; int kl;
                if (kg < kSplit) { Ap = Af0; kl = kg; } else { Ap = Af1; kl = kg - kSplit; }
                va[j] = Ap[(long)b * strideAb + (long)kl * M + m0 + m];
            }
        } else {
            #pragma unroll
            for (int p = 0; p < 2; ++p)
                pa[p] = *(const uint4*)(Ah_g + (long)b * strideAb +
                                        (long)(m0 + sRow + p * 64) * K + kk + sOct * 8);
        }
    };
    auto loadB = [&](int kk) {
        #pragma unroll
        for (int p = 0; p < BSEG; ++p)
            pb[p] = *(const uint4*)(Bh_g + (long)(n0 + sRow + p * 64) * K + kk + sOct * 8);
    };
    auto storeAB = [&]() {
        if (A_F32KM) {
            int m = tid & 127, half = tid >> 7;
            #pragma unroll
            for (int o = 0; o < 2; ++o) {
                uint4 h;
                h.x = pk2h(va[o*8+0], va[o*8+1]);
                h.y = pk2h(va[o*8+2], va[o*8+3]);
                h.z = pk2h(va[o*8+4], va[o*8+5]);
                h.w = pk2h(va[o*8+6], va[o*8+7]);
                *(uint4*)&Ah[m][half*16 + o*8] = h;
            }
        } else {
            #pragma unroll
            for (int p = 0; p < 2; ++p)
                *(uint4*)&Ah[sRow + p*64][sOct*8] = pa[p];
        }
        #pragma unroll
        for (int p = 0; p < BSEG; ++p)
            *(uint4*)&Bh[sRow + p*64][sOct*8] = pb[p];
    };

    loadA(0); loadB(0);
    for (int kk = 0; kk < K; kk += 32) {
        storeAB();
        __syncthreads();
        if (kk + 32 < K) { loadA(kk + 32); loadB(kk + 32); }
        f16x8 bh[NT];
        #pragma unroll
        for (int nt = 0; nt < NT; ++nt)
            bh[nt] = *(const f16x8*)&Bh[wc*NT*16 + nt*16 + lrow][loct*8];
        #pragma unroll
        for (int mt = 0; mt < MT; ++mt) {
            f16x8 ah = *(const f16x8*)&Ah[wr*MT*16 + mt*16 + lrow][loct*8];
            #pragma unroll
            for (int nt = 0; nt < NT; ++nt)
                acc[mt][nt] = __builtin_amdgcn_mfma_f32_16x16x32_f16(ah, bh[nt], acc[mt][nt], 0, 0, 0);
        }
        __syncthreads();
    }
    // epilogue: C/D col=lane&15, row=(lane>>4)*4+reg
    #pragma unroll
    for (int mt = 0; mt < MT; ++mt) {
        #pragma unroll
        for (int r4 = 0; r4 < 4; ++r4) {
            int m = m0 + wr*MT*16 + mt * 16 + loct * 4 + r4;
            long rowb = (long)b * M + m;
            #pragma unroll
            for (int nt = 0; nt < NT; ++nt) {
                int n = n0 + wc*NT*16 + nt * 16 + lrow;
                float v = acc[mt][nt][r4];
                if (EPI == HEPI_XP) {
                    Oh0[rowb * N + n] = __float2half(v + bias[n]);
                } else if (EPI == HEPI_UZ) {
                    if (n < DIN) Oh0[rowb * DIN + n] = __float2half(v);
                    else         Oh1[rowb * DIN + (n - DIN)] = __float2half(v);
                } else {
                    O0[rowb * N + n] = v;
                }
            }
        }
    }
}

// ================= 3-plane split-bf16 MFMA GEMM (D34: delta path, exact) ==========
__global__ __launch_bounds__(256)
void mfma_d34(const unsigned* __restrict__ Apk, const unsigned* __restrict__ Bpk,
              const float* __restrict__ bias,
              float* __restrict__ Od, float* __restrict__ Ob, float* __restrict__ Oc,
              int M, int N, int K, long strideAb, int nBlk)
{
    constexpr int MT = 4, NT = 4, BN = 128, BSEG = 2;
    __shared__ __align__(16) unsigned short Ah[128][LDK], Al[128][LDK];
    __shared__ __align__(16) unsigned short Bh[BN][LDK],  Bl[BN][LDK];
    const int mBlk = M / 128;
    const int bid = blockIdx.x;
    const int r = bid & 7, q = bid >> 3;
    const int ni = q % nBlk;
    const int mg = (q / nBlk) * 8 + r;
    const int b = mg / mBlk, m_idx = mg - b * mBlk;
    const int n0 = ni * BN, m0 = m_idx * 128;
    const int tid  = threadIdx.x;
    const int lane = tid & 63;
    const int w    = tid >> 6;
    const int wr   = w >> 1, wc = w & 1;
    const int lrow = lane & 15;
    const int loct = lane >> 4;

    f32x4 acc[MT][NT];
    #pragma unroll
    for (int i = 0; i < MT; ++i)
        #pragma unroll
        for (int j = 0; j < NT; ++j)
            acc[i][j] = (f32x4){0.f, 0.f, 0.f, 0.f};

    const int sOct = tid & 3, sRow = tid >> 2;
    uint4 pa[2][2], pb[BSEG][2];

    auto loadA = [&](int kk) {
        #pragma unroll
        for (int p = 0; p < 2; ++p) {
            const unsigned* g = Apk + (long)b * strideAb + (long)(m0 + sRow + p * 64) * K + kk + sOct * 8;
            pa[p][0] = *(const uint4*)g;
            pa[p][1] = *(const uint4*)(g + 4);
        }
    };
    auto loadB = [&](int kk) {
        #pragma unroll
        for (int p = 0; p < BSEG; ++p) {
            int ng = n0 + sRow + p * 64;
            if (ng >= N) {
                pb[p][0] = make_uint4(0, 0, 0, 0);
                pb[p][1] = make_uint4(0, 0, 0, 0);
            } else {
                const unsigned* g = Bpk + (long)ng * K + kk + sOct * 8;
                pb[p][0] = *(const uint4*)g;
                pb[p][1] = *(const uint4*)(g + 4);
            }
        }
    };
    auto storeAB = [&]() {
        #pragma unroll
        for (int p = 0; p < 2; ++p) {
            uint4 h, l;
            unpack8(pa[p][0], pa[p][1], h, l);
            *(uint4*)&Ah[sRow + p*64][sOct*8] = h;
            *(uint4*)&Al[sRow + p*64][sOct*8] = l;
        }
        #pragma unroll
        for (int p = 0; p < BSEG; ++p) {
            uint4 h, l;
            unpack8(pb[p][0], pb[p][1], h, l);
            *(uint4*)&Bh[sRow + p*64][sOct*8] = h;
            *(uint4*)&Bl[sRow + p*64][sOct*8] = l;
        }
    };

    loadA(0); loadB(0);
    for (int kk = 0; kk < K; kk += 32) {
        storeAB();
        __syncthreads();
        if (kk + 32 < K) { loadA(kk + 32); loadB(kk + 32); }
        bf16x8 bh[NT], bl2[NT];
        #pragma unroll
        for (int nt = 0; nt < NT; ++nt) {
            bh[nt]  = *(const bf16x8*)&Bh[wc*NT*16 + nt*16 + lrow][loct*8];
            bl2[nt] = *(const bf16x8*)&Bl[wc*NT*16 + nt*16 + lrow][loct*8];
        }
        #pragma unroll
        for (int mt = 0; mt < MT; ++mt) {
            bf16x8 ah  = *(const bf16x8*)&Ah[wr*MT*16 + mt*16 + lrow][loct*8];
            bf16x8 al2 = *(const bf16x8*)&Al[wr*MT*16 + mt*16 + lrow][loct*8];
            #pragma unroll
            for (int nt = 0; nt < NT; ++nt) {
                acc[mt][nt] = __builtin_amdgcn_mfma_f32_16x16x32_bf16(ah,  bh[nt],  acc[mt][nt], 0, 0, 0);
                acc[mt][nt] = __builtin_amdgcn_mfma_f32_16x16x32_bf16(ah,  bl2[nt], acc[mt][nt], 0, 0, 0);
                acc[mt][nt] = __builtin_amdgcn_mfma_f32_16x16x32_bf16(al2, bh[nt],  acc[mt][nt], 0, 0, 0);
            }
        }
        __syncthreads();
    }
    #pragma unroll
    for (int mt = 0; mt < MT; ++mt) {
        #pragma unroll
        for (int r4 = 0; r4 < 4; ++r4) {
            int m = m0 + wr*MT*16 + mt * 16 + loct * 4 + r4;
            long rowb = (long)b * M + m;
            #pragma unroll
            for (int nt = 0; nt < NT; ++nt) {
                int n = n0 + wc*NT*16 + nt * 16 + lrow;
                float v = acc[mt][nt][r4];
                if (n < DIN)            Od[rowb * DIN + n] = softplus_fast(v + bias[n]);
                else if (n < DIN + 16)  Ob[rowb * 16 + (n - DIN)] = v;
                else if (n < DIN + 32)  Oc[rowb * 16 + (n - DIN - 16)] = v;
            }
        }
    }
}

// ---------------- merged weight prep: Wp/Win/Wout -> fp16; Wcomb -> packed split ----
#define SZ_WP  131072
#define SZ_WIN 262144
#define SZ_WO  131072
#define SZ_WC  278528
__global__ __launch_bounds__(256)
void pack_all(const float* __restrict__ Wp, const float* __restrict__ Win,
              const float* __restrict__ Wout, const float* __restrict__ Wdt,
              const float* __restrict__ Wx,
              __half* __restrict__ wph, __half* __restrict__ winh,
              __half* __restrict__ woh, unsigned* __restrict__ wc)
{
    int i = blockIdx.x * 256 + threadIdx.x;
    if (i < SZ_WP) { wph[i] = __float2half(Wp[i]); return; }
    i -= SZ_WP;
    if (i < SZ_WIN) { winh[i] = __float2half(Win[i]); return; }
    i -= SZ_WIN;
    if (i < SZ_WO) { woh[i] = __float2half(Wout[i]); return; }
    i -= SZ_WO;
    if (i < SZ_WC) {
        int n = i >> 9, k = i & 511;
        float acc;
        if (n < DIN) {
            acc = 0.f;
            #pragma unroll
            for (int rr = 0; rr < DTR; ++rr)
                acc += Wdt[n * DTR + rr] * Wx[rr * DIN + k];
        } else {
            acc = Wx[(DTR + (n - DIN)) * DIN + k];
        }
        wc[i] = packsplit(acc);
    }
}

// ---------------- depthwise causal conv (k=4) + silu: fp16 in -> packed u ---------
__global__ __launch_bounds__(256)
void conv_silu_kernel(const __half* __restrict__ u_pre, const float* __restrict__ cw,
                      const float* __restrict__ cb, unsigned* __restrict__ upk)
{
    long idx = (long)blockIdx.x * blockDim.x + threadIdx.x;
    int d = (int)(idx % DIN);
    long bl = idx / DIN;
    int l = (int)(bl % L);
    long brow = bl - l;
    float v = cb[d];
    #pragma unroll
    for (int j = 0; j < 4; ++j) {
        int li = l - 3 + j;
        if (li >= 0) v += __half2float(u_pre[(brow + li) * DIN + d]) * cw[d * 4 + j];
    }
    upk[idx] = packsplit(silu_f(v));
}

// ---------------- chunked parallel selective scan, d-per-lane ----------------
#define NC 128
#define LC (L / NC)

__global__ __launch_bounds__(256)
void scan_phase1(const float* __restrict__ delta, const unsigned* __restrict__ upk,
                 const float* __restrict__ Bm, const float* __restrict__ A_log,
                 float* __restrict__ Asum, float* __restrict__ Xsum)
{
    __shared__ float sB[LC][DSTATE];
    const int gd = blockIdx.x & 1;
    const int c  = (blockIdx.x >> 1) & (NC - 1);
    const int b  = blockIdx.x >> 8;
    const int d  = gd * 256 + threadIdx.x;
    const int t0 = c * LC;
    float Arow[DSTATE];
    #pragma unroll
    for (int q = 0; q < 4; ++q) {
        float4 v = *(const float4*)&A_log[d * DSTATE + q * 4];
        Arow[q * 4 + 0] = -__expf(v.x);
        Arow[q * 4 + 1] = -__expf(v.y);
        Arow[q * 4 + 2] = -__expf(v.z);
        Arow[q * 4 + 3] = -__expf(v.w);
    }
    for (int i = threadIdx.x; i < LC * DSTATE; i += 256)
        sB[i >> 4][i & 15] = Bm[((long)b * L + t0 + (i >> 4)) * DSTATE + (i & 15)];
    __syncthreads();
    float P[DSTATE], X[DSTATE];
    #pragma unroll
    for (int s = 0; s < DSTATE; ++s) { P[s] = 1.f; X[s] = 0.f; }
    for (int t = 0; t < LC; ++t) {
        long gidx = ((long)b * L + t0 + t) * DIN + d;
        float dlt = delta[gidx];
        float du  = dlt * unpackf(upk[gidx]);
        #pragma unroll
        for (int s = 0; s < DSTATE; ++s) {
            float a = __expf(dlt * Arow[s]);
            P[s] *= a;
            X[s] = a * X[s] + du * sB[t][s];
        }
    }
    long o = (((long)b * NC + c) * DIN + d) * DSTATE;
    #pragma unroll
    for (int q = 0; q < 4; ++q) {
        *(float4*)&Asum[o + q * 4] = make_float4(P[q*4], P[q*4+1], P[q*4+2], P[q*4+3]);
        *(float4*)&Xsum[o + q * 4] = make_float4(X[q*4], X[q*4+1], X[q*4+2], X[q*4+3]);
    }
}

__global__ __launch_bounds__(256)
void scan_phase2(const float* __restrict__ Asum, float* __restrict__ Xsum)
{
    int lane = blockIdx.x * 256 + threadIdx.x;
    int b = lane / (DIN * DSTATE);
    int rem = lane % (DIN * DSTATE);
    float h = 0.f;
    for (int c = 0; c < NC; ++c) {
        long idx = ((long)b * NC + c) * (DIN * DSTATE) + rem;
        float A = Asum[idx], X = Xsum[idx];
        Xsum[idx] = h;
        h = A * h + X;
    }
}

__global__ __launch_bounds__(256)
void scan_phase3(const float* __restrict__ delta, const unsigned* __restrict__ upk,
                 const float* __restrict__ Bm, const float* __restrict__ Cm,
                 const __half* __restrict__ z, const float* __restrict__ A_log,
                 const float* __restrict__ Dp, const float* __restrict__ Hinit,
                 __half* __restrict__ y2h)
{
    __shared__ float sB[LC][DSTATE], sC[LC][DSTATE];
    const int gd = blockIdx.x & 1;
    const int c  = (blockIdx.x >> 1) & (NC - 1);
    const int b  = blockIdx.x >> 8;
    const int d  = gd * 256 + threadIdx.x;
    const int t0 = c * LC;
    float Arow[DSTATE];
    #pragma unroll
    for (int q = 0; q < 4; ++q) {
        float4 v = *(const float4*)&A_log[d * DSTATE + q * 4];
        Arow[q * 4 + 0] = -__expf(v.x);
        Arow[q * 4 + 1] = -__expf(v.y);
        Arow[q * 4 + 2] = -__expf(v.z);
        Arow[q * 4 + 3] = -__expf(v.w);
    }
    for (int i = threadIdx.x; i < LC * DSTATE; i += 256) {
        long gidx = ((long)b * L + t0 + (i >> 4)) * DSTATE + (i & 15);
        sB[i >> 4][i & 15] = Bm[gidx];
        sC[i >> 4][i & 15] = Cm[gidx];
    }
    float h[DSTATE];
    {
        long o = (((long)b * NC + c) * DIN + d) * DSTATE;
        #pragma unroll
        for (int q = 0; q < 4; ++q) {
            float4 v = *(const float4*)&Hinit[o + q * 4];
            h[q * 4 + 0] = v.x; h[q * 4 + 1] = v.y;
            h[q * 4 + 2] = v.z; h[q * 4 + 3] = v.w;
        }
    }
    const float Dval = Dp[d];
    __syncthreads();
    for (int t = 0; t < LC; ++t) {
        long gidx = ((long)b * L + t0 + t) * DIN + d;
        float dlt = delta[gidx];
        float uu  = unpackf(upk[gidx]);
        float zz  = __half2float(z[gidx]);
        float du  = dlt * uu;
        float y = 0.f;
        #pragma unroll
        for (int s = 0; s < DSTATE; ++s) {
            float a = __expf(dlt * Arow[s]);
            h[s] = h[s] * a + du * sB[t][s];
            y += h[s] * sC[t][s];
        }
        y2h[gidx] = __float2half((y + uu * Dval) * silu_f(zz));
    }
}

// ---------------- LayerNorm over C + transpose to (B,C,L) ----------------
__global__ __launch_bounds__(256)
void ln_kernel(const float* __restrict__ X, const float* __restrict__ gamma,
               const float* __restrict__ beta, float* __restrict__ out)
{
    __shared__ float tile[32][257];
    __shared__ float sMu[32], sRs[32];
    const int l0 = blockIdx.x * 32;
    const int b  = blockIdx.y;
    const int tid = threadIdx.x;
    for (int i = tid; i < 32 * 256; i += 256) {
        int l = i >> 8, c = i & 255;
        tile[l][c] = X[((long)b * L + l0 + l) * CDIM + c];
    }
    __syncthreads();
    {
        int l = tid >> 3, sub = tid & 7;
        float s1 = 0.f, s2 = 0.f;
        for (int c = sub * 32; c < sub * 32 + 32; ++c) {
            float v = tile[l][c];
            s1 += v; s2 += v * v;
        }
        s1 += __shfl_xor(s1, 1); s2 += __shfl_xor(s2, 1);
        s1 += __shfl_xor(s1, 2); s2 += __shfl_xor(s2, 2);
        s1 += __shfl_xor(s1, 4); s2 += __shfl_xor(s2, 4);
        if (sub == 0) {
            float mu = s1 * (1.f / 256.f);
            float var = s2 * (1.f / 256.f) - mu * mu;
            sMu[l] = mu;
            sRs[l] = rsqrtf(var + 1e-5f);
        }
    }
    __syncthreads();
    for (int i = tid; i < 32 * 256; i += 256) {
        int ll = i & 31, c = i >> 5;
        float v = (tile[ll][c] - sMu[ll]) * sRs[ll] * gamma[c] + beta[c];
        out[((long)b * CDIM + c) * L + l0 + ll] = v;
    }
}

extern "C" void kernel_launch(void* const* d_in, const int* in_sizes, int n_in,
                              void* d_out, int out_size, void* d_ws, size_t ws_size,
                              hipStream_t stream)
{
    const float* sp   = (const float*)d_in[0];
    const float* fq   = (const float*)d_in[1];
    const float* Wp   = (const float*)d_in[2];
    const float* bp   = (const float*)d_in[3];
    const float* Win  = (const float*)d_in[4];
    const float* cw   = (const float*)d_in[5];
    const float* cb   = (const float*)d_in[6];
    const float* Wx   = (const float*)d_in[7];
    const float* Wdt  = (const float*)d_in[8];
    const float* bdt  = (const float*)d_in[9];
    const float* Alog = (const float*)d_in[10];
    const float* Dp   = (const float*)d_in[11];
    const float* Wout = (const float*)d_in[12];
    const float* gam  = (const float*)d_in[13];
    const float* bet  = (const float*)d_in[14];
    float* out = (float*)d_out;
    float* ws  = (float*)d_ws;

    const size_t NLD = (size_t)BATCH * L * DIN;   // 8.39M
    const size_t NLC = (size_t)BATCH * L * CDIM;  // 4.19M

    size_t off = 0;
    float*    delta = ws + off; off += NLD;               // fp32 delta (dedicated)
    unsigned* upk   = (unsigned*)(ws + off); off += NLD;  // packed-split u
    __half*   u16   = (__half*)(ws + off); off += NLD / 2;
    __half*   z16   = (__half*)(ws + off); off += NLD / 2;
    __half*   y16   = (__half*)(ws + off); off += NLD / 2;
    __half*   xp16  = (__half*)(ws + off); off += NLC / 2;
    float*    xmix  = ws + off; off += NLC;
    __half*   wph   = (__half*)(ws + off); off += SZ_WP / 2;
    __half*   winh  = (__half*)(ws + off); off += SZ_WIN / 2;
    __half*   woh   = (__half*)(ws + off); off += SZ_WO / 2;
    unsigned* wc_pk = (unsigned*)(ws + off); off += SZ_WC;
    float*    Bmb   = ws + off; off += (size_t)BATCH * L * DSTATE;
    float*    Cmb   = ws + off; off += (size_t)BATCH * L * DSTATE;
    float*    Asum  = ws + off; off += (size_t)BATCH * NC * DIN * DSTATE;
    float*    Xsum  = ws + off; off += (size_t)BATCH * NC * DIN * DSTATE;

    dim3 blk(256);
    pack_all<<<dim3((SZ_WP + SZ_WIN + SZ_WO + SZ_WC) / 256), blk, 0, stream>>>(
        Wp, Win, Wout, Wdt, Wx, wph, winh, woh, wc_pk);

    // GEMM1 (fp16): x_proj = x_cat @ Wp^T + bp  (A fp32 K-major; MT=4,NT=2, nBlk=4)
    hgemm<HEPI_XP, true, 4, 2><<<dim3(BATCH * (L/128) * 4), blk, 0, stream>>>(
        sp, fq, nullptr, wph, bp, nullptr, xp16, nullptr,
        L, CDIM, 2 * CDIM, CDIM, (long)CDIM * L, 4);
    // GEMM2 (fp16): xz = x_proj @ Win^T -> u16 / z16  (MT=4,NT=4, nBlk=8)
    hgemm<HEPI_UZ, false, 4, 4><<<dim3(BATCH * (L/128) * 8), blk, 0, stream>>>(
        nullptr, nullptr, xp16, winh, nullptr, nullptr, u16, z16,
        L, 2 * DIN, CDIM, 1 << 30, (long)L * CDIM, 8);
    conv_silu_kernel<<<dim3((int)(NLD / 256)), blk, 0, stream>>>(u16, cw, cb, upk);
    // D34 (3-plane bf16, exact): [delta | Bm | Cm] = u @ Wcomb^T
    mfma_d34<<<dim3(BATCH * (L/128) * 5), blk, 0, stream>>>(
        upk, wc_pk, bdt, delta, Bmb, Cmb, L, 544, DIN, (long)L * DIN, 5);

    scan_phase1<<<dim3(BATCH * NC * 2), blk, 0, stream>>>(delta, upk, Bmb, Alog, Asum, Xsum);
    scan_phase2<<<dim3(BATCH * DIN * DSTATE / 256), blk, 0, stream>>>(Asum, Xsum);
    scan_phase3<<<dim3(BATCH * NC * 2), blk, 0, stream>>>(
        delta, upk, Bmb, Cmb, z16, Alog, Dp, Xsum, y16);

    // GEMM5 (fp16): x_mixed = y2 @ Wout^T  (MT=4,NT=2, nBlk=4)
    hgemm<HEPI_F32, false, 4, 2><<<dim3(BATCH * (L/128) * 4), blk, 0, stream>>>(
        nullptr, nullptr, y16, woh, nullptr, xmix, nullptr, nullptr,
        L, CDIM, DIN, 1 << 30, (long)L * DIN, 4);
    ln_kernel<<<dim3(L / 32, BATCH), blk, 0, stream>>>(xmix, gam, bet, out);
}